// Round 1
// baseline (12453.101 us; speedup 1.0000x reference)
//
#include <hip/hip_runtime.h>
#include <math.h>

#define T_STEPS 64
#define BATCH   32
#define SEQ     64
#define HID     512
#define VOCAB   32000
#define ABASE   16000   // outs (A-matrix) band: f32 cols [16000,16512) of each logits row
#define SBASE   16512   // fp32 state band: f32 cols [16512,16576)
#define NBLK    256

typedef unsigned short u16;
typedef unsigned int   u32;

typedef __attribute__((ext_vector_type(8))) short short8;
typedef __attribute__((ext_vector_type(4))) float f32x4;

__device__ __forceinline__ u16 f2bf(float f) {
  u32 x = __float_as_uint(f);
  u32 r = (x + 0x7fffu + ((x >> 16) & 1u)) >> 16;
  return (u16)r;
}
__device__ __forceinline__ float sigf(float x) { return 1.0f / (1.0f + expf(-x)); }

// fp32 state element i lives at logits row (i>>6), f32 col SBASE + (i&63).
// float4 access valid when i % 4 == 0 (never crosses a row).
__device__ __forceinline__ float* stP(float* o, int i) {
  return o + (size_t)(i >> 6) * VOCAB + SBASE + (i & 63);
}
// state map (floats): h0 bufs @ 0 / 16384 ; h1 bufs @ 32768 / 49152 ;
//                     q @ 65536 ; ctx @ 81920 ; sync words @ 98304 (row 1536)
// c0/c1 live in registers of the persistent kernel (block-owned units).

// ---------------------------------------------------------------------------
// grid barrier: generation barrier, device-scope atomics. 256 co-resident
// blocks (1/CU guaranteed: 141KB LDS/block -> exactly 1 block/CU, grid==256).
// ---------------------------------------------------------------------------
__device__ __forceinline__ void gsync(unsigned* sp) {
  __syncthreads();
  if (threadIdx.x == 0) {
    __threadfence();
    unsigned* cnt = sp;
    unsigned* gen = sp + 16;   // 64B apart
    unsigned g = __hip_atomic_load(gen, __ATOMIC_RELAXED, __HIP_MEMORY_SCOPE_AGENT);
    unsigned a = __hip_atomic_fetch_add(cnt, 1u, __ATOMIC_ACQ_REL, __HIP_MEMORY_SCOPE_AGENT);
    if (a == NBLK - 1) {
      __hip_atomic_store(cnt, 0u, __ATOMIC_RELAXED, __HIP_MEMORY_SCOPE_AGENT);
      __hip_atomic_store(gen, g + 1u, __ATOMIC_RELEASE, __HIP_MEMORY_SCOPE_AGENT);
    } else {
      while (__hip_atomic_load(gen, __ATOMIC_ACQUIRE, __HIP_MEMORY_SCOPE_AGENT) == g)
        __builtin_amdgcn_s_sleep(2);
    }
    __threadfence();
  }
  __syncthreads();
}

// ---------------------------------------------------------------------------
// xs staging: 32 batches x 512 floats, stored as float4 slots [k4][b] with an
// XOR swizzle so BOTH the staging write (lanes = consecutive k4, fixed b) and
// the compute read (lanes = consecutive b, fixed k4) are bank-minimal.
// ---------------------------------------------------------------------------
__device__ __forceinline__ int xslot(int k4, int bb) {
  return (k4 * 32 + (bb ^ (k4 & 7))) * 4;
}
__device__ __forceinline__ void stage_band(float* o, int base, float* xs) {
  const int tid = threadIdx.x;
#pragma unroll
  for (int it = 0; it < 16; ++it) {
    int f = it * 256 + tid;
    int bb = f >> 7, k4 = f & 127;
    *(float4*)&xs[xslot(k4, bb)] = *(const float4*)stP(o, base + bb * 512 + k4 * 4);
  }
}
__device__ __forceinline__ void stage_emb(const int* __restrict__ tokens,
                                          const float* __restrict__ emb,
                                          int t, float* xs) {
  const int tid = threadIdx.x;
#pragma unroll
  for (int it = 0; it < 16; ++it) {
    int f = it * 256 + tid;
    int bb = f >> 7, k4 = f & 127;
    int tok = tokens[bb * T_STEPS + t];
    *(float4*)&xs[xslot(k4, bb)] = *(const float4*)(emb + (size_t)tok * HID + k4 * 4);
  }
}
template <int N>
__device__ __forceinline__ float dotN(const float* xs, const float* wrow,
                                      int k4base, int wofs, int bb) {
  float ax = 0.f, ay = 0.f, az = 0.f, aw = 0.f;
#pragma unroll 8
  for (int i = 0; i < N; ++i) {
    int k4 = k4base + i;
    float4 x = *(const float4*)&xs[xslot(k4, bb)];
    float4 w = *(const float4*)&wrow[wofs + i * 4];
    ax += w.x * x.x; ay += w.y * x.y; az += w.z * x.z; aw += w.w * x.w;
  }
  return (ax + ay) + (az + aw);
}
// gl[gq*32+b] holds gate pre-activations; gq = q*2 + du (q = gate, du = unit)
__device__ __forceinline__ void lstm_gate_tail(float* o, float* gl, int bk,
                                               int hout_base, float& creg, int tid) {
  if (tid < 64) {
    int b2 = tid & 31, du = tid >> 5, u = bk * 2 + du;
    float iv = sigf(gl[du * 32 + b2]);
    float fv = sigf(gl[(2 + du) * 32 + b2]);
    float gv = tanhf(gl[(4 + du) * 32 + b2]);
    float ov = sigf(gl[(6 + du) * 32 + b2]);
    float cn = fv * creg + iv * gv;
    creg = cn;
    *stP(o, hout_base + b2 * 512 + u) = ov * tanhf(cn);
  }
}

// ---------------------------------------------------------------------------
// Persistent kernel: all 64 timesteps. Block bk owns gate rows
// j = q*512 + bk*2 + {0,1} of both LSTM layers (weights LDS-resident),
// q/out rows bk*2 + {0,1} of Wai/Wao, and c-state of units 2bk,2bk+1 (regs).
// Per step: PH1 [L1(t) + out(t-1)] | PH2 [L0(t+1) + q(t)] | PH3 [softmax/ctx].
// ---------------------------------------------------------------------------
#define SMEM_FLOATS 36176
#define SMEM_BYTES  (SMEM_FLOATS * 4)

__global__ void __launch_bounds__(256, 1) persist_kernel(
    float* o, const int* __restrict__ tokens, const float* __restrict__ emb,
    const float* __restrict__ Wih, const float* __restrict__ Whh,
    const float* __restrict__ bih, const float* __restrict__ bhh,
    const float* __restrict__ Wai, const float* __restrict__ Wao,
    const float* __restrict__ h0in, const float* __restrict__ c0in,
    const float* __restrict__ context,
    float* __restrict__ o_h, float* __restrict__ o_c, float* __restrict__ o_attn,
    unsigned* syncp)
{
  extern __shared__ float smem[];
  float* wih0  = smem;            // 8*512
  float* whh0  = smem + 4096;
  float* wih1  = smem + 8192;
  float* whh1  = smem + 12288;
  float* waiL  = smem + 16384;    // 2*512
  float* waoL  = smem + 17408;    // 2*1024
  float* xs    = smem + 19456;    // 16384 staged input vectors
  float* gl    = smem + 35840;    // 256 reduce buffer
  float* bias0 = smem + 36096;    // 8
  float* bias1 = smem + 36104;    // 8
  float* at_s  = smem + 36112;    // 64

  const int tid = threadIdx.x;
  const int bk  = blockIdx.x;
  const int b   = tid & 31;
  const int gq  = tid >> 5;

  // ---- load persistent weights into LDS (once) ----
  for (int f = tid; f < 1024; f += 256) {        // 8 rows x 128 float4
    int r = f >> 7, k4 = f & 127;
    size_t j0 = (size_t)((r >> 1) * HID + bk * 2 + (r & 1));
    *(float4*)&wih0[r * 512 + k4 * 4] = *(const float4*)(Wih + j0 * HID + k4 * 4);
    *(float4*)&whh0[r * 512 + k4 * 4] = *(const float4*)(Whh + j0 * HID + k4 * 4);
    *(float4*)&wih1[r * 512 + k4 * 4] = *(const float4*)(Wih + 1048576 + j0 * HID + k4 * 4);
    *(float4*)&whh1[r * 512 + k4 * 4] = *(const float4*)(Whh + 1048576 + j0 * HID + k4 * 4);
  }
  {
    int r = tid >> 7, k4 = tid & 127;            // wai: 2 rows x 128 float4
    *(float4*)&waiL[r * 512 + k4 * 4] =
        *(const float4*)(Wai + (size_t)(bk * 2 + r) * HID + k4 * 4);
  }
  for (int f = tid; f < 512; f += 256) {         // wao: 2 rows x 256 float4
    int r = f >> 8, k4 = f & 255;
    *(float4*)&waoL[r * 1024 + k4 * 4] =
        *(const float4*)(Wao + (size_t)(bk * 2 + r) * 2 * HID + k4 * 4);
  }
  if (tid < 8) {
    int j0 = (tid >> 1) * HID + bk * 2 + (tid & 1);
    bias0[tid] = bih[j0] + bhh[j0];
    bias1[tid] = bih[2048 + j0] + bhh[2048 + j0];
  }
  // ---- c state in regs; h(-1) into band (buf1 for both layers) ----
  float c0r = 0.f, c1r = 0.f;
  if (tid < 64) {
    int b2 = tid & 31, du = tid >> 5, u = bk * 2 + du;
    c0r = c0in[b2 * 512 + u];
    c1r = c0in[16384 + b2 * 512 + u];
    *stP(o, 16384 + b2 * 512 + u) = h0in[b2 * 512 + u];          // h0(-1)
    *stP(o, 49152 + b2 * 512 + u) = h0in[16384 + b2 * 512 + u];  // h1(-1)
  }
  gsync(syncp);

  // ---- PH0: L0(0) -> h0(0) in buf0 ----
  {
    stage_emb(tokens, emb, 0, xs); __syncthreads();
    float acc = bias0[gq] + dotN<128>(xs, &wih0[gq * 512], 0, 0, b);
    __syncthreads();
    stage_band(o, 16384, xs); __syncthreads();                    // h0(-1)
    acc += dotN<128>(xs, &whh0[gq * 512], 0, 0, b);
    gl[tid] = acc; __syncthreads();
    lstm_gate_tail(o, gl, bk, 0, c0r, tid);
    gsync(syncp);
  }

  for (int t = 0; t < T_STEPS; ++t) {
    const int p = t & 1;

    // ===== PH1: L1(t) + out(t-1) =====
    stage_band(o, p * 16384, xs); __syncthreads();                // h0(t)
    float acc = bias1[gq] + dotN<128>(xs, &wih1[gq * 512], 0, 0, b);
    __syncthreads();
    stage_band(o, 32768 + (p ^ 1) * 16384, xs); __syncthreads();  // h1(t-1)
    acc += dotN<128>(xs, &whh1[gq * 512], 0, 0, b);
    float op = 0.f;                                               // out h1-half
    if (t > 0 && gq >= 4)
      op = dotN<64>(xs, &waoL[(gq & 1) * 1024], ((gq >> 1) - 2) * 64,
                    512 + ((gq >> 1) - 2) * 256, b);
    gl[tid] = acc; __syncthreads();
    lstm_gate_tail(o, gl, bk, 32768 + p * 16384, c1r, tid);       // h1(t)
    if (t > 0) stage_band(o, 81920, xs);                          // ctx(t-1)
    __syncthreads();
    if (t > 0 && gq < 4)                                          // out ctx-half
      op = dotN<64>(xs, &waoL[(gq & 1) * 1024], (gq >> 1) * 64, (gq >> 1) * 256, b);
    gl[tid] = op; __syncthreads();
    if (t > 0 && tid < 64) {
      int d = tid >> 5, b2 = tid & 31;
      float s = gl[d * 32 + b2] + gl[(2 + d) * 32 + b2]
              + gl[(4 + d) * 32 + b2] + gl[(6 + d) * 32 + b2];
      o[(size_t)((t - 1) * BATCH + b2) * VOCAB + ABASE + bk * 2 + d] = tanhf(s);
    }
    gsync(syncp);

    // ===== PH2: L0(t+1) + q(t) =====
    if (t + 1 < T_STEPS) {
      stage_emb(tokens, emb, t + 1, xs); __syncthreads();
      float a0 = bias0[gq] + dotN<128>(xs, &wih0[gq * 512], 0, 0, b);
      __syncthreads();
      stage_band(o, p * 16384, xs); __syncthreads();              // h0(t)
      a0 += dotN<128>(xs, &whh0[gq * 512], 0, 0, b);
      gl[tid] = a0; __syncthreads();
      lstm_gate_tail(o, gl, bk, (p ^ 1) * 16384, c0r, tid);       // h0(t+1)
    }
    stage_band(o, 32768 + p * 16384, xs); __syncthreads();        // h1(t)
    {
      float qp = dotN<32>(xs, &waiL[(gq & 1) * 512], (gq >> 1) * 32,
                          (gq >> 1) * 128, b);
      gl[tid] = qp; __syncthreads();
      if (tid < 64) {
        int d = tid >> 5, b2 = tid & 31;
        float s = gl[d * 32 + b2] + gl[(2 + d) * 32 + b2]
                + gl[(4 + d) * 32 + b2] + gl[(6 + d) * 32 + b2];
        *stP(o, 65536 + b2 * 512 + bk * 2 + d) = s;               // q(t)
      }
    }
    gsync(syncp);

    // ===== PH3: scores/softmax/ctx (blocks 0..31, one per batch) =====
    if (bk < 32) {
      const int bb = bk;
      if (tid < 128)
        *(float4*)&xs[tid * 4] = *(const float4*)stP(o, 65536 + bb * 512 + tid * 4);
      __syncthreads();
      {
        int s = tid >> 2, kc = tid & 3;
        const float* crow = context + ((size_t)bb * SEQ + s) * HID + kc * 128;
        float ax = 0.f, ay = 0.f, az = 0.f, aw = 0.f;
#pragma unroll 8
        for (int i = 0; i < 32; ++i) {
          float4 c4 = *(const float4*)(crow + i * 4);
          const float* q4 = &xs[kc * 128 + i * 4];
          ax += c4.x * q4[0]; ay += c4.y * q4[1];
          az += c4.z * q4[2]; aw += c4.w * q4[3];
        }
        gl[tid] = (ax + ay) + (az + aw);
      }
      __syncthreads();
      if (tid < 64) {
        float sc = gl[tid * 4] + gl[tid * 4 + 1] + gl[tid * 4 + 2] + gl[tid * 4 + 3];
        float m = sc;
#pragma unroll
        for (int off = 32; off > 0; off >>= 1) m = fmaxf(m, __shfl_xor(m, off));
        float e = expf(sc - m);
        float su = e;
#pragma unroll
        for (int off = 32; off > 0; off >>= 1) su += __shfl_xor(su, off);
        float av = e / su;
        at_s[tid] = av;
        if (t == T_STEPS - 1) o_attn[bb * SEQ + tid] = av;
      }
      __syncthreads();
#pragma unroll
      for (int jj = 0; jj < 2; ++jj) {
        int h = tid + jj * 256;
        float a2 = 0.f;
#pragma unroll 4
        for (int s2 = 0; s2 < SEQ; ++s2)
          a2 += at_s[s2] * context[((size_t)bb * SEQ + s2) * HID + h];
        *stP(o, 81920 + bb * 512 + h) = a2;                       // ctx(t)
      }
    }
    gsync(syncp);
  }

  // ===== epilogue: out(63) + final states =====
  {
    stage_band(o, 49152, xs); __syncthreads();                    // h1(63)
    float op = 0.f;
    if (gq >= 4)
      op = dotN<64>(xs, &waoL[(gq & 1) * 1024], ((gq >> 1) - 2) * 64,
                    512 + ((gq >> 1) - 2) * 256, b);
    __syncthreads();
    stage_band(o, 81920, xs); __syncthreads();                    // ctx(63)
    if (gq < 4)
      op = dotN<64>(xs, &waoL[(gq & 1) * 1024], (gq >> 1) * 64, (gq >> 1) * 256, b);
    gl[tid] = op; __syncthreads();
    if (tid < 64) {
      int d = tid >> 5, b2 = tid & 31;
      float s = gl[d * 32 + b2] + gl[(2 + d) * 32 + b2]
              + gl[(4 + d) * 32 + b2] + gl[(6 + d) * 32 + b2];
      o[(size_t)(2016 + b2) * VOCAB + ABASE + bk * 2 + d] = tanhf(s);
    }
  }
  if (tid < 64) {
    int b2 = tid & 31, du = tid >> 5, u = bk * 2 + du;
    o_h[b2 * 512 + u]         = *stP(o, 16384 + b2 * 512 + u);    // h0(63)
    o_h[16384 + b2 * 512 + u] = *stP(o, 49152 + b2 * 512 + u);    // h1(63)
    o_c[b2 * 512 + u]         = c0r;
    o_c[16384 + b2 * 512 + u] = c1r;
  }
}

// ---------------------------------------------------------------------------
// vocab GEMM pass A: 490 col-tiles avoiding cols [16000,16640).
// ---------------------------------------------------------------------------
__device__ __forceinline__ short8 pack8(const float* p) {
  float4 a = *(const float4*)p, b = *(const float4*)(p + 4);
  short8 r;
  r[0] = (short)f2bf(a.x); r[1] = (short)f2bf(a.y);
  r[2] = (short)f2bf(a.z); r[3] = (short)f2bf(a.w);
  r[4] = (short)f2bf(b.x); r[5] = (short)f2bf(b.y);
  r[6] = (short)f2bf(b.z); r[7] = (short)f2bf(b.w);
  return r;
}

__global__ __launch_bounds__(256) void vocab_gemm_a(
    float* o, const float* __restrict__ Bw, const float* __restrict__ bias)
{
  __shared__ __align__(16) u16 As[4 * 64 * 8];
  __shared__ __align__(16) u16 Bs[4 * 64 * 8];
  const int tid = threadIdx.x;
  const int wv   = tid >> 6;
  const int lane = tid & 63;
  const int m16  = lane & 15;
  const int quad = lane >> 4;
  const int ct = (blockIdx.x < 250) ? blockIdx.x : blockIdx.x + 10;
  const int rowBase = blockIdx.y * 64;
  const int colBase = ct * 64;
  const int srow = tid >> 2;
  const int scg  = tid & 3;
  f32x4 acc[4];
#pragma unroll
  for (int nt = 0; nt < 4; ++nt)
#pragma unroll
    for (int r = 0; r < 4; ++r) acc[nt][r] = 0.f;

  for (int k0 = 0; k0 < HID; k0 += 32) {
    __syncthreads();
    *(short8*)&As[(scg * 64 + srow) * 8] =
        pack8(&o[(size_t)(rowBase + srow) * VOCAB + ABASE + k0 + scg * 8]);
    *(short8*)&Bs[(scg * 64 + srow) * 8] =
        pack8(&Bw[(size_t)(colBase + srow) * HID + k0 + scg * 8]);
    __syncthreads();
    short8 a = *(const short8*)&As[(quad * 64 + wv * 16 + m16) * 8];
#pragma unroll
    for (int nt = 0; nt < 4; ++nt) {
      short8 bfr = *(const short8*)&Bs[(quad * 64 + nt * 16 + m16) * 8];
      acc[nt] = __builtin_amdgcn_mfma_f32_16x16x32_bf16(a, bfr, acc[nt], 0, 0, 0);
    }
  }
#pragma unroll
  for (int nt = 0; nt < 4; ++nt) {
    int col = colBase + nt * 16 + m16;
    float bv = bias[col];
#pragma unroll
    for (int r = 0; r < 4; ++r) {
      int row = rowBase + wv * 16 + quad * 4 + r;
      o[(size_t)row * VOCAB + col] = acc[nt][r] + bv;
    }
  }
}

// ---------------------------------------------------------------------------
// pass B: the 10 band col-tiles. A staged to LDS BEFORE any write.
// ---------------------------------------------------------------------------
__global__ __launch_bounds__(256) void vocab_gemm_b(
    float* o, const float* __restrict__ Bw, const float* __restrict__ bias)
{
  __shared__ __align__(16) u16 As[32 * 512];   // 32 KB bf16
  const int tid = threadIdx.x;
  const int rowBase = blockIdx.x * 32;
  for (int i = tid; i < 2048; i += 256) {      // 2048 chunks of 8
    int r = i >> 6, kk = (i & 63) * 8;
    *(short8*)&As[r * 512 + kk] =
        pack8(&o[(size_t)(rowBase + r) * VOCAB + ABASE + kk]);
  }
  __syncthreads();
  const int lane = tid & 63, w = tid >> 6;
  const int m16 = lane & 15, quad = lane >> 4;
  const int rg = w & 1, cg = w >> 1;
  for (int ctile = 250; ctile < 260; ++ctile) {
    int colBase = ctile * 64 + cg * 32;
    f32x4 acc[2];
#pragma unroll
    for (int nt = 0; nt < 2; ++nt)
#pragma unroll
      for (int r = 0; r < 4; ++r) acc[nt][r] = 0.f;
    for (int k0 = 0; k0 < HID; k0 += 32) {
      short8 a = *(const short8*)&As[(rg * 16 + m16) * 512 + k0 + quad * 8];
#pragma unroll
      for (int nt = 0; nt < 2; ++nt) {
        short8 bfr = pack8(&Bw[(size_t)(colBase + nt * 16 + m16) * HID + k0 + quad * 8]);
        acc[nt] = __builtin_amdgcn_mfma_f32_16x16x32_bf16(a, bfr, acc[nt], 0, 0, 0);
      }
    }
#pragma unroll
    for (int nt = 0; nt < 2; ++nt) {
      int col = colBase + nt * 16 + m16;
      float bv = bias[col];
#pragma unroll
      for (int r = 0; r < 4; ++r) {
        int row = rowBase + rg * 16 + quad * 4 + r;
        o[(size_t)row * VOCAB + col] = acc[nt][r] + bv;
      }
    }
  }
}

// ---------------------------------------------------------------------------
// log-softmax over V=32000, 3-pass global (rows are L2/L3-hot)
// ---------------------------------------------------------------------------
__global__ __launch_bounds__(256) void logsoftmax_kernel(float* logits)
{
  __shared__ float red[256];
  const int tid = threadIdx.x;
  float* rowp = logits + (size_t)blockIdx.x * VOCAB;
  float mx = -1e30f;
  for (int i = tid; i < VOCAB / 4; i += 256) {
    float4 v = ((const float4*)rowp)[i];
    mx = fmaxf(mx, fmaxf(fmaxf(v.x, v.y), fmaxf(v.z, v.w)));
  }
  red[tid] = mx; __syncthreads();
  for (int s = 128; s > 0; s >>= 1) {
    if (tid < s) red[tid] = fmaxf(red[tid], red[tid + s]);
    __syncthreads();
  }
  mx = red[0]; __syncthreads();
  float sum = 0.f;
  for (int i = tid; i < VOCAB / 4; i += 256) {
    float4 v = ((const float4*)rowp)[i];
    sum += expf(v.x - mx) + expf(v.y - mx) + expf(v.z - mx) + expf(v.w - mx);
  }
  red[tid] = sum; __syncthreads();
  for (int s = 128; s > 0; s >>= 1) {
    if (tid < s) red[tid] += red[tid + s];
    __syncthreads();
  }
  float lse = mx + logf(red[0]);
  for (int i = tid; i < VOCAB / 4; i += 256) {
    float4 v = ((const float4*)rowp)[i];
    float4 ov;
    ov.x = v.x - lse; ov.y = v.y - lse; ov.z = v.z - lse; ov.w = v.w - lse;
    ((float4*)rowp)[i] = ov;
  }
}

// ---------------------------------------------------------------------------
extern "C" void kernel_launch(void* const* d_in, const int* in_sizes, int n_in,
                              void* d_out, int out_size, void* d_ws, size_t ws_size,
                              hipStream_t stream)
{
  (void)in_sizes; (void)n_in; (void)out_size; (void)d_ws; (void)ws_size;
  const int*   tokens  = (const int*)d_in[0];
  const float* h0      = (const float*)d_in[1];
  const float* c0      = (const float*)d_in[2];
  const float* context = (const float*)d_in[3];
  const float* emb     = (const float*)d_in[4];
  const float* Wih     = (const float*)d_in[5];
  const float* Whh     = (const float*)d_in[6];
  const float* bih     = (const float*)d_in[7];
  const float* bhh     = (const float*)d_in[8];
  const float* Wai     = (const float*)d_in[9];
  const float* Wao     = (const float*)d_in[10];
  const float* Wlin    = (const float*)d_in[11];
  const float* blin    = (const float*)d_in[12];

  float* o      = (float*)d_out;
  float* o_h    = o + (size_t)2048 * VOCAB;
  float* o_c    = o_h + 32768;
  float* o_attn = o_c + 32768;
  unsigned* syncp = (unsigned*)(o + (size_t)1536 * VOCAB + SBASE);  // row 1536 band

  hipFuncSetAttribute((const void*)persist_kernel,
                      hipFuncAttributeMaxDynamicSharedMemorySize, SMEM_BYTES);
  hipMemsetAsync(syncp, 0, 128, stream);
  persist_kernel<<<NBLK, 256, SMEM_BYTES, stream>>>(
      o, tokens, emb, Wih, Whh, bih, bhh, Wai, Wao,
      h0, c0, context, o_h, o_c, o_attn, syncp);

  vocab_gemm_a<<<dim3(490, 32), 256, 0, stream>>>(o, Wlin, blin);
  vocab_gemm_b<<<64, 256, 0, stream>>>(o, Wlin, blin);
  logsoftmax_kernel<<<2048, 256, 0, stream>>>(o);
}

// Round 2
// 6154.661 us; speedup vs baseline: 2.0234x; 2.0234x over previous
//
#include <hip/hip_runtime.h>
#include <math.h>

#define T_STEPS 64
#define BATCH   32
#define SEQ     64
#define HID     512
#define VOCAB   32000
#define ABASE   16000   // outs (A-matrix) band: f32 cols [16000,16512) of each logits row
#define SBASE   16512   // fp32 state band: f32 cols [16512,16576)
#define NBLK    256

typedef unsigned short u16;
typedef unsigned int   u32;

typedef __attribute__((ext_vector_type(8))) short short8;
typedef __attribute__((ext_vector_type(4))) float f32x4;

__device__ __forceinline__ u16 f2bf(float f) {
  u32 x = __float_as_uint(f);
  u32 r = (x + 0x7fffu + ((x >> 16) & 1u)) >> 16;
  return (u16)r;
}
__device__ __forceinline__ float sigf(float x) { return 1.0f / (1.0f + expf(-x)); }

// fp32 state element i lives at logits row (i>>6), f32 col SBASE + (i&63).
__device__ __forceinline__ float* stP(float* o, int i) {
  return o + (size_t)(i >> 6) * VOCAB + SBASE + (i & 63);
}
// state map (floats): h0 bufs @ 0 / 16384 (h0(t) in buf[t&1]);
//                     h1 bufs @ 32768 / 49152 (h1(t) in buf[t&1]);
//                     q @ 65536 ; ctx @ 81920 ; sync words rows 1536..1541.

// sync word i -> band rows 1536+ (free until vocab_gemm_b)
__device__ __forceinline__ unsigned* syncW(float* o, int i) {
  return (unsigned*)(o + (size_t)(1536 + (i >> 6)) * VOCAB + SBASE + (i & 63));
}

// ---------------------------------------------------------------------------
// flag-based grid barrier: no RMW contention. Blocks 1..255 release-publish
// into their own word; block 0's threads poll them in parallel and bump gen.
// Monotonic generation (memset to 0 each launch), agent-scope atomics (sc1:
// bypass non-coherent per-XCD L2). One threadfence per block per barrier side.
// ---------------------------------------------------------------------------
__device__ __forceinline__ void gsync(float* o, unsigned g) {
  const int tid = threadIdx.x;
  __syncthreads();
  if (blockIdx.x == 0) {
    if (tid >= 1) {   // poll arrival words of blocks 1..255 (one per thread)
      while (__hip_atomic_load(syncW(o, tid), __ATOMIC_RELAXED,
                               __HIP_MEMORY_SCOPE_AGENT) < g)
        __builtin_amdgcn_s_sleep(4);
    }
    __syncthreads();
    if (tid == 0) {
      __threadfence();   // publish block0 writes + invalidate stale lines
      __hip_atomic_store(syncW(o, 320), g, __ATOMIC_RELAXED,
                         __HIP_MEMORY_SCOPE_AGENT);
    }
    __syncthreads();
  } else {
    if (tid == 0) {
      __threadfence();   // release: flush this XCD's L2 dirty lines
      __hip_atomic_store(syncW(o, blockIdx.x), g, __ATOMIC_RELAXED,
                         __HIP_MEMORY_SCOPE_AGENT);
      while (__hip_atomic_load(syncW(o, 320), __ATOMIC_RELAXED,
                               __HIP_MEMORY_SCOPE_AGENT) < g)
        __builtin_amdgcn_s_sleep(4);
      __threadfence();   // acquire: invalidate stale lines
    }
    __syncthreads();
  }
}

// ---------------------------------------------------------------------------
// xs staging: 32 batches x 512 floats as float4 slots [k4][b], XOR-swizzled.
// ---------------------------------------------------------------------------
__device__ __forceinline__ int xslot(int k4, int bb) {
  return (k4 * 32 + (bb ^ (k4 & 7))) * 4;
}
__device__ __forceinline__ void stage_band(float* o, int base, float* xs) {
  const int tid = threadIdx.x;
#pragma unroll
  for (int it = 0; it < 16; ++it) {
    int f = it * 256 + tid;
    int bb = f >> 7, k4 = f & 127;
    *(float4*)&xs[xslot(k4, bb)] = *(const float4*)stP(o, base + bb * 512 + k4 * 4);
  }
}
__device__ __forceinline__ void stage_emb(const int* __restrict__ tokens,
                                          const float* __restrict__ emb,
                                          int t, float* xs) {
  const int tid = threadIdx.x;
#pragma unroll
  for (int it = 0; it < 16; ++it) {
    int f = it * 256 + tid;
    int bb = f >> 7, k4 = f & 127;
    int tok = tokens[bb * T_STEPS + t];
    *(float4*)&xs[xslot(k4, bb)] = *(const float4*)(emb + (size_t)tok * HID + k4 * 4);
  }
}
template <int N>
__device__ __forceinline__ float dotN(const float* xs, const float* wrow,
                                      int k4base, int wofs, int bb) {
  float ax = 0.f, ay = 0.f, az = 0.f, aw = 0.f;
#pragma unroll 8
  for (int i = 0; i < N; ++i) {
    int k4 = k4base + i;
    float4 x = *(const float4*)&xs[xslot(k4, bb)];
    float4 w = *(const float4*)&wrow[wofs + i * 4];
    ax += w.x * x.x; ay += w.y * x.y; az += w.z * x.z; aw += w.w * x.w;
  }
  return (ax + ay) + (az + aw);
}
// glx[gq*32+b], gq = q*2+du (q = gate 0..3, du = unit 0..1); cs LDS c-state.
__device__ __forceinline__ void gate_tail(float* o, const float* glx, float* cs,
                                          int bk, int hout_base, int tl) {
  int b2 = tl & 31, du = tl >> 5, u = bk * 2 + du;
  float iv = sigf(glx[du * 32 + b2]);
  float fv = sigf(glx[(2 + du) * 32 + b2]);
  float gv = tanhf(glx[(4 + du) * 32 + b2]);
  float ov = sigf(glx[(6 + du) * 32 + b2]);
  float cn = fv * cs[du * 32 + b2] + iv * gv;
  cs[du * 32 + b2] = cn;
  *stP(o, hout_base + b2 * 512 + u) = ov * tanhf(cn);
}

// ---------------------------------------------------------------------------
// Persistent kernel: all 64 timesteps, 2 grid barriers per step.
// Phase A (all 256 blocks): finish out(t-2) [ctx-half], L1(t), L0(t+1),
//   q(t-1), h1-half of out(t-1) -> oph (persistent LDS).
// Phase B (blocks 0..31): softmax(q(t-1)) -> ctx(t-1).
// ---------------------------------------------------------------------------
#define SMEM_FLOATS 37200
#define SMEM_BYTES  (SMEM_FLOATS * 4)

__global__ void __launch_bounds__(256, 1) persist_kernel(
    float* o, const int* __restrict__ tokens, const float* __restrict__ emb,
    const float* __restrict__ Wih, const float* __restrict__ Whh,
    const float* __restrict__ bih, const float* __restrict__ bhh,
    const float* __restrict__ Wai, const float* __restrict__ Wao,
    const float* __restrict__ h0in, const float* __restrict__ c0in,
    const float* __restrict__ context,
    float* __restrict__ o_h, float* __restrict__ o_c, float* __restrict__ o_attn)
{
  extern __shared__ float smem[];
  float* wih0  = smem;            // 8*512
  float* whh0  = smem + 4096;
  float* wih1  = smem + 8192;
  float* whh1  = smem + 12288;
  float* waiL  = smem + 16384;    // 2*512
  float* waoL  = smem + 17408;    // 2*1024
  float* xs    = smem + 19456;    // 16384 staged input vectors
  float* gl    = smem + 35840;    // 256 (L1 gates)
  float* gl2   = smem + 36096;    // 256 (L0 gates)
  float* gl3   = smem + 36352;    // 256 (q partials)
  float* glo   = smem + 36608;    // 256 (out ctx-half partials)
  float* oph   = smem + 36864;    // 128 (out h1-half partials, persistent)
  float* c0s   = smem + 36992;    // 64
  float* c1s   = smem + 37056;    // 64
  float* bias0 = smem + 37120;    // 8
  float* bias1 = smem + 37128;    // 8 (+pad)
  float* at_s  = smem + 37136;    // 64

  const int tid = threadIdx.x;
  const int bk  = blockIdx.x;
  const int b   = tid & 31;
  const int gq  = tid >> 5;
  unsigned g = 0;

  // ---- load persistent weights into LDS (once) ----
  for (int f = tid; f < 1024; f += 256) {        // 8 rows x 128 float4 each
    int r = f >> 7, k4 = f & 127;
    size_t j0 = (size_t)((r >> 1) * HID + bk * 2 + (r & 1));
    *(float4*)&wih0[r * 512 + k4 * 4] = *(const float4*)(Wih + j0 * HID + k4 * 4);
    *(float4*)&whh0[r * 512 + k4 * 4] = *(const float4*)(Whh + j0 * HID + k4 * 4);
    *(float4*)&wih1[r * 512 + k4 * 4] = *(const float4*)(Wih + 1048576 + j0 * HID + k4 * 4);
    *(float4*)&whh1[r * 512 + k4 * 4] = *(const float4*)(Whh + 1048576 + j0 * HID + k4 * 4);
  }
  {
    int r = tid >> 7, k4 = tid & 127;            // wai: 2 rows x 128 float4
    *(float4*)&waiL[r * 512 + k4 * 4] =
        *(const float4*)(Wai + (size_t)(bk * 2 + r) * HID + k4 * 4);
  }
  for (int f = tid; f < 512; f += 256) {         // wao: 2 rows x 256 float4
    int r = f >> 8, k4 = f & 255;
    *(float4*)&waoL[r * 1024 + k4 * 4] =
        *(const float4*)(Wao + (size_t)(bk * 2 + r) * 2 * HID + k4 * 4);
  }
  if (tid < 8) {
    int j0 = (tid >> 1) * HID + bk * 2 + (tid & 1);
    bias0[tid] = bih[j0] + bhh[j0];
    bias1[tid] = bih[2048 + j0] + bhh[2048 + j0];
  }
  // ---- P0: c state to LDS, h(-1) into buf1 bands ----
  if (tid < 64) {
    int b2 = tid & 31, du = tid >> 5, u = bk * 2 + du;
    c0s[du * 32 + b2] = c0in[b2 * 512 + u];
    c1s[du * 32 + b2] = c0in[16384 + b2 * 512 + u];
    *stP(o, 16384 + b2 * 512 + u) = h0in[b2 * 512 + u];          // h0(-1)
    *stP(o, 49152 + b2 * 512 + u) = h0in[16384 + b2 * 512 + u];  // h1(-1)
  }
  gsync(o, ++g);

  // ---- P1: L0(0) -> h0(0) (buf0) ----
  {
    stage_emb(tokens, emb, 0, xs); __syncthreads();
    float a0 = bias0[gq] + dotN<128>(xs, &wih0[gq * 512], 0, 0, b);
    __syncthreads();
    stage_band(o, 16384, xs); __syncthreads();                    // h0(-1)
    a0 += dotN<128>(xs, &whh0[gq * 512], 0, 0, b);
    gl2[tid] = a0; __syncthreads();
    if (tid >= 64 && tid < 128) gate_tail(o, gl2, c0s, bk, 0, tid - 64);
    gsync(o, ++g);
  }

  for (int t = 0; t < T_STEPS; ++t) {
    // ===== Phase A =====
    if (t >= 2) {                                                 // finish out(t-2)
      stage_band(o, 81920, xs); __syncthreads();                  // ctx(t-2)
      float cp = 0.f;
      if (gq < 4)
        cp = dotN<64>(xs, &waoL[(gq & 1) * 1024], (gq >> 1) * 64, (gq >> 1) * 256, b);
      glo[tid] = cp; __syncthreads();
      if (tid < 64) {
        int d = tid >> 5, b2 = tid & 31;
        float s = glo[d * 32 + b2] + glo[(2 + d) * 32 + b2]
                + oph[d * 32 + b2] + oph[(2 + d) * 32 + b2];
        o[(size_t)((t - 2) * BATCH + b2) * VOCAB + ABASE + bk * 2 + d] = tanhf(s);
      }
    }
    float a0 = 0.f;
    __syncthreads();
    if (t + 1 < T_STEPS) {
      stage_emb(tokens, emb, t + 1, xs); __syncthreads();
      a0 = bias0[gq] + dotN<128>(xs, &wih0[gq * 512], 0, 0, b);
    }
    __syncthreads();
    stage_band(o, (t & 1) * 16384, xs); __syncthreads();          // h0(t)
    if (t + 1 < T_STEPS) a0 += dotN<128>(xs, &whh0[gq * 512], 0, 0, b);
    float a1 = bias1[gq] + dotN<128>(xs, &wih1[gq * 512], 0, 0, b);
    __syncthreads();
    stage_band(o, 32768 + ((t + 1) & 1) * 16384, xs); __syncthreads();  // h1(t-1)
    a1 += dotN<128>(xs, &whh1[gq * 512], 0, 0, b);
    float qp = 0.f;
    if (t >= 1) {
      if (gq >= 4)                                                // h1-half of out(t-1)
        oph[(gq - 4) * 32 + b] =
            dotN<64>(xs, &waoL[(gq & 1) * 1024], ((gq >> 1) - 2) * 64,
                     512 + ((gq >> 1) - 2) * 256, b);
      qp = dotN<32>(xs, &waiL[(gq & 1) * 512], (gq >> 1) * 32, (gq >> 1) * 128, b);
    }
    gl[tid] = a1; gl2[tid] = a0; gl3[tid] = qp;
    __syncthreads();
    if (tid < 64) {
      gate_tail(o, gl, c1s, bk, 32768 + (t & 1) * 16384, tid);    // h1(t)
    } else if (tid < 128) {
      if (t + 1 < T_STEPS)
        gate_tail(o, gl2, c0s, bk, ((t + 1) & 1) * 16384, tid - 64); // h0(t+1)
    } else if (tid < 192 && t >= 1) {
      int tl = tid - 128, d = tl >> 5, b2 = tl & 31;
      float s = gl3[d * 32 + b2] + gl3[(2 + d) * 32 + b2]
              + gl3[(4 + d) * 32 + b2] + gl3[(6 + d) * 32 + b2];
      *stP(o, 65536 + b2 * 512 + bk * 2 + d) = s;                 // q(t-1)
    }
    gsync(o, ++g);

    // ===== Phase B: softmax/ctx(t-1), blocks 0..31 =====
    if (bk < 32 && t >= 1) {
      const int bb = bk;
      if (tid < 128)
        *(float4*)&xs[tid * 4] = *(const float4*)stP(o, 65536 + bb * 512 + tid * 4);
      __syncthreads();
      {
        int s = tid >> 2, kc = tid & 3;
        const float* crow = context + ((size_t)bb * SEQ + s) * HID + kc * 128;
        float ax = 0.f, ay = 0.f, az = 0.f, aw = 0.f;
#pragma unroll 8
        for (int i = 0; i < 32; ++i) {
          float4 c4 = *(const float4*)(crow + i * 4);
          const float* q4 = &xs[kc * 128 + i * 4];
          ax += c4.x * q4[0]; ay += c4.y * q4[1];
          az += c4.z * q4[2]; aw += c4.w * q4[3];
        }
        gl[tid] = (ax + ay) + (az + aw);
      }
      __syncthreads();
      if (tid < 64) {
        float sc = gl[tid * 4] + gl[tid * 4 + 1] + gl[tid * 4 + 2] + gl[tid * 4 + 3];
        float m = sc;
#pragma unroll
        for (int off = 32; off > 0; off >>= 1) m = fmaxf(m, __shfl_xor(m, off));
        float e = expf(sc - m);
        float su = e;
#pragma unroll
        for (int off = 32; off > 0; off >>= 1) su += __shfl_xor(su, off);
        at_s[tid] = e / su;
      }
      __syncthreads();
#pragma unroll
      for (int jj = 0; jj < 2; ++jj) {
        int h = tid + jj * 256;
        float a2 = 0.f;
#pragma unroll 4
        for (int s2 = 0; s2 < SEQ; ++s2)
          a2 += at_s[s2] * context[((size_t)bb * SEQ + s2) * HID + h];
        *stP(o, 81920 + bb * 512 + h) = a2;                       // ctx(t-1)
      }
    }
    gsync(o, ++g);
  }

  // ===== E1: finish out(62); oph(63) + q(63) =====
  {
    stage_band(o, 81920, xs); __syncthreads();                    // ctx(62)
    float cp = 0.f;
    if (gq < 4)
      cp = dotN<64>(xs, &waoL[(gq & 1) * 1024], (gq >> 1) * 64, (gq >> 1) * 256, b);
    glo[tid] = cp; __syncthreads();
    if (tid < 64) {
      int d = tid >> 5, b2 = tid & 31;
      float s = glo[d * 32 + b2] + glo[(2 + d) * 32 + b2]
              + oph[d * 32 + b2] + oph[(2 + d) * 32 + b2];
      o[(size_t)(62 * BATCH + b2) * VOCAB + ABASE + bk * 2 + d] = tanhf(s);
    }
    __syncthreads();
    stage_band(o, 49152, xs); __syncthreads();                    // h1(63)
    if (gq >= 4)
      oph[(gq - 4) * 32 + b] =
          dotN<64>(xs, &waoL[(gq & 1) * 1024], ((gq >> 1) - 2) * 64,
                   512 + ((gq >> 1) - 2) * 256, b);
    float qp = dotN<32>(xs, &waiL[(gq & 1) * 512], (gq >> 1) * 32, (gq >> 1) * 128, b);
    gl3[tid] = qp; __syncthreads();
    if (tid >= 128 && tid < 192) {
      int tl = tid - 128, d = tl >> 5, b2 = tl & 31;
      float s = gl3[d * 32 + b2] + gl3[(2 + d) * 32 + b2]
              + gl3[(4 + d) * 32 + b2] + gl3[(6 + d) * 32 + b2];
      *stP(o, 65536 + b2 * 512 + bk * 2 + d) = s;                 // q(63)
    }
    gsync(o, ++g);
  }
  // ===== E2: softmax(63) -> ctx(63) + o_attn =====
  if (bk < 32) {
    const int bb = bk;
    if (tid < 128)
      *(float4*)&xs[tid * 4] = *(const float4*)stP(o, 65536 + bb * 512 + tid * 4);
    __syncthreads();
    {
      int s = tid >> 2, kc = tid & 3;
      const float* crow = context + ((size_t)bb * SEQ + s) * HID + kc * 128;
      float ax = 0.f, ay = 0.f, az = 0.f, aw = 0.f;
#pragma unroll 8
      for (int i = 0; i < 32; ++i) {
        float4 c4 = *(const float4*)(crow + i * 4);
        const float* q4 = &xs[kc * 128 + i * 4];
        ax += c4.x * q4[0]; ay += c4.y * q4[1];
        az += c4.z * q4[2]; aw += c4.w * q4[3];
      }
      gl[tid] = (ax + ay) + (az + aw);
    }
    __syncthreads();
    if (tid < 64) {
      float sc = gl[tid * 4] + gl[tid * 4 + 1] + gl[tid * 4 + 2] + gl[tid * 4 + 3];
      float m = sc;
#pragma unroll
      for (int off = 32; off > 0; off >>= 1) m = fmaxf(m, __shfl_xor(m, off));
      float e = expf(sc - m);
      float su = e;
#pragma unroll
      for (int off = 32; off > 0; off >>= 1) su += __shfl_xor(su, off);
      float av = e / su;
      at_s[tid] = av;
      o_attn[bb * SEQ + tid] = av;                                // attn(63)
    }
    __syncthreads();
#pragma unroll
    for (int jj = 0; jj < 2; ++jj) {
      int h = tid + jj * 256;
      float a2 = 0.f;
#pragma unroll 4
      for (int s2 = 0; s2 < SEQ; ++s2)
        a2 += at_s[s2] * context[((size_t)bb * SEQ + s2) * HID + h];
      *stP(o, 81920 + bb * 512 + h) = a2;                         // ctx(63)
    }
  }
  gsync(o, ++g);
  // ===== E3: finish out(63); final states =====
  {
    stage_band(o, 81920, xs); __syncthreads();                    // ctx(63)
    float cp = 0.f;
    if (gq < 4)
      cp = dotN<64>(xs, &waoL[(gq & 1) * 1024], (gq >> 1) * 64, (gq >> 1) * 256, b);
    glo[tid] = cp; __syncthreads();
    if (tid < 64) {
      int d = tid >> 5, b2 = tid & 31;
      float s = glo[d * 32 + b2] + glo[(2 + d) * 32 + b2]
              + oph[d * 32 + b2] + oph[(2 + d) * 32 + b2];
      o[(size_t)(63 * BATCH + b2) * VOCAB + ABASE + bk * 2 + d] = tanhf(s);
    }
  }
  if (tid < 64) {
    int b2 = tid & 31, du = tid >> 5, u = bk * 2 + du;
    o_h[b2 * 512 + u]         = *stP(o, 16384 + b2 * 512 + u);    // h0(63) buf1
    o_h[16384 + b2 * 512 + u] = *stP(o, 49152 + b2 * 512 + u);    // h1(63) buf1
    o_c[b2 * 512 + u]         = c0s[du * 32 + b2];
    o_c[16384 + b2 * 512 + u] = c1s[du * 32 + b2];
  }
}

// ---------------------------------------------------------------------------
// vocab GEMM pass A: 490 col-tiles avoiding cols [16000,16640).
// ---------------------------------------------------------------------------
__device__ __forceinline__ short8 pack8(const float* p) {
  float4 a = *(const float4*)p, b = *(const float4*)(p + 4);
  short8 r;
  r[0] = (short)f2bf(a.x); r[1] = (short)f2bf(a.y);
  r[2] = (short)f2bf(a.z); r[3] = (short)f2bf(a.w);
  r[4] = (short)f2bf(b.x); r[5] = (short)f2bf(b.y);
  r[6] = (short)f2bf(b.z); r[7] = (short)f2bf(b.w);
  return r;
}

__global__ __launch_bounds__(256) void vocab_gemm_a(
    float* o, const float* __restrict__ Bw, const float* __restrict__ bias)
{
  __shared__ __align__(16) u16 As[4 * 64 * 8];
  __shared__ __align__(16) u16 Bs[4 * 64 * 8];
  const int tid = threadIdx.x;
  const int wv   = tid >> 6;
  const int lane = tid & 63;
  const int m16  = lane & 15;
  const int quad = lane >> 4;
  const int ct = (blockIdx.x < 250) ? blockIdx.x : blockIdx.x + 10;
  const int rowBase = blockIdx.y * 64;
  const int colBase = ct * 64;
  const int srow = tid >> 2;
  const int scg  = tid & 3;
  f32x4 acc[4];
#pragma unroll
  for (int nt = 0; nt < 4; ++nt)
#pragma unroll
    for (int r = 0; r < 4; ++r) acc[nt][r] = 0.f;

  for (int k0 = 0; k0 < HID; k0 += 32) {
    __syncthreads();
    *(short8*)&As[(scg * 64 + srow) * 8] =
        pack8(&o[(size_t)(rowBase + srow) * VOCAB + ABASE + k0 + scg * 8]);
    *(short8*)&Bs[(scg * 64 + srow) * 8] =
        pack8(&Bw[(size_t)(colBase + srow) * HID + k0 + scg * 8]);
    __syncthreads();
    short8 a = *(const short8*)&As[(quad * 64 + wv * 16 + m16) * 8];
#pragma unroll
    for (int nt = 0; nt < 4; ++nt) {
      short8 bfr = *(const short8*)&Bs[(quad * 64 + nt * 16 + m16) * 8];
      acc[nt] = __builtin_amdgcn_mfma_f32_16x16x32_bf16(a, bfr, acc[nt], 0, 0, 0);
    }
  }
#pragma unroll
  for (int nt = 0; nt < 4; ++nt) {
    int col = colBase + nt * 16 + m16;
    float bv = bias[col];
#pragma unroll
    for (int r = 0; r < 4; ++r) {
      int row = rowBase + wv * 16 + quad * 4 + r;
      o[(size_t)row * VOCAB + col] = acc[nt][r] + bv;
    }
  }
}

// ---------------------------------------------------------------------------
// pass B: the 10 band col-tiles. A staged to LDS BEFORE any write.
// ---------------------------------------------------------------------------
__global__ __launch_bounds__(256) void vocab_gemm_b(
    float* o, const float* __restrict__ Bw, const float* __restrict__ bias)
{
  __shared__ __align__(16) u16 As[32 * 512];   // 32 KB bf16
  const int tid = threadIdx.x;
  const int rowBase = blockIdx.x * 32;
  for (int i = tid; i < 2048; i += 256) {      // 2048 chunks of 8
    int r = i >> 6, kk = (i & 63) * 8;
    *(short8*)&As[r * 512 + kk] =
        pack8(&o[(size_t)(rowBase + r) * VOCAB + ABASE + kk]);
  }
  __syncthreads();
  const int lane = tid & 63, w = tid >> 6;
  const int m16 = lane & 15, quad = lane >> 4;
  const int rg = w & 1, cg = w >> 1;
  for (int ctile = 250; ctile < 260; ++ctile) {
    int colBase = ctile * 64 + cg * 32;
    f32x4 acc[2];
#pragma unroll
    for (int nt = 0; nt < 2; ++nt)
#pragma unroll
      for (int r = 0; r < 4; ++r) acc[nt][r] = 0.f;
    for (int k0 = 0; k0 < HID; k0 += 32) {
      short8 a = *(const short8*)&As[(rg * 16 + m16) * 512 + k0 + quad * 8];
#pragma unroll
      for (int nt = 0; nt < 2; ++nt) {
        short8 bfr = pack8(&Bw[(size_t)(colBase + nt * 16 + m16) * HID + k0 + quad * 8]);
        acc[nt] = __builtin_amdgcn_mfma_f32_16x16x32_bf16(a, bfr, acc[nt], 0, 0, 0);
      }
    }
#pragma unroll
    for (int nt = 0; nt < 2; ++nt) {
      int col = colBase + nt * 16 + m16;
      float bv = bias[col];
#pragma unroll
      for (int r = 0; r < 4; ++r) {
        int row = rowBase + rg * 16 + quad * 4 + r;
        o[(size_t)row * VOCAB + col] = acc[nt][r] + bv;
      }
    }
  }
}

// ---------------------------------------------------------------------------
// log-softmax over V=32000, 3-pass global (rows are L2/L3-hot)
// ---------------------------------------------------------------------------
__global__ __launch_bounds__(256) void logsoftmax_kernel(float* logits)
{
  __shared__ float red[256];
  const int tid = threadIdx.x;
  float* rowp = logits + (size_t)blockIdx.x * VOCAB;
  float mx = -1e30f;
  for (int i = tid; i < VOCAB / 4; i += 256) {
    float4 v = ((const float4*)rowp)[i];
    mx = fmaxf(mx, fmaxf(fmaxf(v.x, v.y), fmaxf(v.z, v.w)));
  }
  red[tid] = mx; __syncthreads();
  for (int s = 128; s > 0; s >>= 1) {
    if (tid < s) red[tid] = fmaxf(red[tid], red[tid + s]);
    __syncthreads();
  }
  mx = red[0]; __syncthreads();
  float sum = 0.f;
  for (int i = tid; i < VOCAB / 4; i += 256) {
    float4 v = ((const float4*)rowp)[i];
    sum += expf(v.x - mx) + expf(v.y - mx) + expf(v.z - mx) + expf(v.w - mx);
  }
  red[tid] = sum; __syncthreads();
  for (int s = 128; s > 0; s >>= 1) {
    if (tid < s) red[tid] += red[tid + s];
    __syncthreads();
  }
  float lse = mx + logf(red[0]);
  for (int i = tid; i < VOCAB / 4; i += 256) {
    float4 v = ((const float4*)rowp)[i];
    float4 ov;
    ov.x = v.x - lse; ov.y = v.y - lse; ov.z = v.z - lse; ov.w = v.w - lse;
    ((float4*)rowp)[i] = ov;
  }
}

// ---------------------------------------------------------------------------
extern "C" void kernel_launch(void* const* d_in, const int* in_sizes, int n_in,
                              void* d_out, int out_size, void* d_ws, size_t ws_size,
                              hipStream_t stream)
{
  (void)in_sizes; (void)n_in; (void)out_size; (void)d_ws; (void)ws_size;
  const int*   tokens  = (const int*)d_in[0];
  const float* h0      = (const float*)d_in[1];
  const float* c0      = (const float*)d_in[2];
  const float* context = (const float*)d_in[3];
  const float* emb     = (const float*)d_in[4];
  const float* Wih     = (const float*)d_in[5];
  const float* Whh     = (const float*)d_in[6];
  const float* bih     = (const float*)d_in[7];
  const float* bhh     = (const float*)d_in[8];
  const float* Wai     = (const float*)d_in[9];
  const float* Wao     = (const float*)d_in[10];
  const float* Wlin    = (const float*)d_in[11];
  const float* blin    = (const float*)d_in[12];

  float* o      = (float*)d_out;
  float* o_h    = o + (size_t)2048 * VOCAB;
  float* o_c    = o_h + 32768;
  float* o_attn = o_c + 32768;

  // zero the sync words (band rows 1536..1541, 256B each; graph-capture safe)
  for (int r = 0; r < 6; ++r)
    hipMemsetAsync(o + (size_t)(1536 + r) * VOCAB + SBASE, 0, 256, stream);

  hipFuncSetAttribute((const void*)persist_kernel,
                      hipFuncAttributeMaxDynamicSharedMemorySize, SMEM_BYTES);
  persist_kernel<<<NBLK, 256, SMEM_BYTES, stream>>>(
      o, tokens, emb, Wih, Whh, bih, bhh, Wai, Wao,
      h0, c0, context, o_h, o_c, o_attn);

  vocab_gemm_a<<<dim3(490, 32), 256, 0, stream>>>(o, Wlin, blin);
  vocab_gemm_b<<<64, 256, 0, stream>>>(o, Wlin, blin);
  logsoftmax_kernel<<<2048, 256, 0, stream>>>(o);
}

// Round 4
// 5036.843 us; speedup vs baseline: 2.4724x; 1.2219x over previous
//
#include <hip/hip_runtime.h>
#include <math.h>

#define T_STEPS 64
#define BATCH   32
#define SEQ     64
#define HID     512
#define VOCAB   32000
#define ABASE   16000   // outs (A-matrix) band: f32 cols [16000,16512) of each logits row
#define SBASE   16512   // fp32 state band: f32 cols [16512,16576)
#define NBLK    256

typedef unsigned short u16;
typedef unsigned int   u32;

typedef __attribute__((ext_vector_type(8))) short short8;
typedef __attribute__((ext_vector_type(4))) float f32x4;

#define AS_RLX __ATOMIC_RELAXED
#define SC_AGT __HIP_MEMORY_SCOPE_AGENT

__device__ __forceinline__ u16 f2bf(float f) {
  u32 x = __float_as_uint(f);
  u32 r = (x + 0x7fffu + ((x >> 16) & 1u)) >> 16;
  return (u16)r;
}
__device__ __forceinline__ float sigf(float x) { return 1.0f / (1.0f + expf(-x)); }

// fp32 state element i lives at logits row (i>>6), f32 col SBASE + (i&63).
__device__ __forceinline__ float* stP(float* o, int i) {
  return o + (size_t)(i >> 6) * VOCAB + SBASE + (i & 63);
}
// state map (floats): h0 bufs @ 0 / 16384 (h0(t) in buf[t&1]);
//                     h1 bufs @ 32768 / 49152 (h1(t) in buf[t&1]);
//                     q @ 65536 ; ctx @ 81920 ; sync words rows 1536..1541.

// ---- coherent (agent-scope, L2-bypassing) band accessors -------------------
// All cross-block state uses 32-bit relaxed agent-scope atomics (sc1): stores
// write through to L3 (die-level coherence point), loads bypass the
// non-coherent per-XCD L2 -> no cache-scan fences needed at barriers.
__device__ __forceinline__ void bst(float* p, float v) {
  __hip_atomic_store(p, v, AS_RLX, SC_AGT);
}
__device__ __forceinline__ float bld(const float* p) {
  return __hip_atomic_load(p, AS_RLX, SC_AGT);
}
__device__ __forceinline__ float2 bld2(const float* p) {
  float2 r;
  r.x = __hip_atomic_load(p + 0, AS_RLX, SC_AGT);
  r.y = __hip_atomic_load(p + 1, AS_RLX, SC_AGT);
  return r;
}
__device__ __forceinline__ float4 bld4(const float* p) {
  float4 r;
  r.x = __hip_atomic_load(p + 0, AS_RLX, SC_AGT);
  r.y = __hip_atomic_load(p + 1, AS_RLX, SC_AGT);
  r.z = __hip_atomic_load(p + 2, AS_RLX, SC_AGT);
  r.w = __hip_atomic_load(p + 3, AS_RLX, SC_AGT);
  return r;
}

// sync word i -> band rows 1536+ (free until vocab_gemm_b)
__device__ __forceinline__ unsigned* syncW(float* o, int i) {
  return (unsigned*)(o + (size_t)(1536 + (i >> 6)) * VOCAB + SBASE + (i & 63));
}

// spin until *w >= g. Self-healing: if the relaxed sc1 load ever serves a
// stale value indefinitely, a periodic threadfence (acquire invalidate)
// repairs visibility -- zero cost on the normal path, prevents livelock.
__device__ __forceinline__ void spin_until(unsigned* w, unsigned g) {
  int k = 0;
  while (__hip_atomic_load(w, AS_RLX, SC_AGT) < g) {
    __builtin_amdgcn_s_sleep(2);
    if (++k == 16384) { k = 0; __threadfence(); }
  }
}

// ---------------------------------------------------------------------------
// fence-free grid barrier. All cross-block state traffic is sc1 write-through,
// so release = per-wave vmcnt(0) drain before the flag store; acquire needs
// nothing (state loads bypass L2). Blocks 1..255 publish their own word;
// block 0's threads poll them in parallel, then block 0 bumps the gen word.
// ---------------------------------------------------------------------------
__device__ __forceinline__ void gsync(float* o, unsigned g) {
  asm volatile("s_waitcnt vmcnt(0)" ::: "memory");   // drain sc1 state stores
  __syncthreads();
  const int tid = threadIdx.x;
  if (blockIdx.x == 0) {
    if (tid >= 1) spin_until(syncW(o, tid), g);   // blocks 1..255 arrival
    __syncthreads();
    if (tid == 0)
      __hip_atomic_store(syncW(o, 320), g, AS_RLX, SC_AGT);
  } else {
    if (tid == 0) {
      __hip_atomic_store(syncW(o, blockIdx.x), g, AS_RLX, SC_AGT);
      spin_until(syncW(o, 320), g);
    }
  }
  __syncthreads();
}

// ---------------------------------------------------------------------------
// xs staging: 32 batches x 512 floats as float4 slots [k4][b], XOR-swizzled.
// ---------------------------------------------------------------------------
__device__ __forceinline__ int xslot(int k4, int bb) {
  return (k4 * 32 + (bb ^ (k4 & 7))) * 4;
}
__device__ __forceinline__ void stage_band(float* o, int base, float* xs) {
  const int tid = threadIdx.x;
#pragma unroll
  for (int it = 0; it < 16; ++it) {
    int f = it * 256 + tid;
    int bb = f >> 7, k4 = f & 127;
    *(float4*)&xs[xslot(k4, bb)] = bld4(stP(o, base + bb * 512 + k4 * 4));
  }
}
__device__ __forceinline__ void stage_emb(const int* __restrict__ tokens,
                                          const float* __restrict__ emb,
                                          int t, float* xs) {
  const int tid = threadIdx.x;
#pragma unroll
  for (int it = 0; it < 16; ++it) {
    int f = it * 256 + tid;
    int bb = f >> 7, k4 = f & 127;
    int tok = tokens[bb * T_STEPS + t];
    *(float4*)&xs[xslot(k4, bb)] = *(const float4*)(emb + (size_t)tok * HID + k4 * 4);
  }
}
template <int N>
__device__ __forceinline__ float dotN(const float* xs, const float* wrow,
                                      int k4base, int wofs, int bb) {
  float ax = 0.f, ay = 0.f, az = 0.f, aw = 0.f;
#pragma unroll 8
  for (int i = 0; i < N; ++i) {
    int k4 = k4base + i;
    float4 x = *(const float4*)&xs[xslot(k4, bb)];
    float4 w = *(const float4*)&wrow[wofs + i * 4];
    ax += w.x * x.x; ay += w.y * x.y; az += w.z * x.z; aw += w.w * x.w;
  }
  return (ax + ay) + (az + aw);
}
// glx[gq*32+b], gq = q*2+du (q = gate 0..3, du = unit 0..1); cs LDS c-state.
__device__ __forceinline__ void gate_tail(float* o, const float* glx, float* cs,
                                          int bk, int hout_base, int tl) {
  int b2 = tl & 31, du = tl >> 5, u = bk * 2 + du;
  float iv = sigf(glx[du * 32 + b2]);
  float fv = sigf(glx[(2 + du) * 32 + b2]);
  float gv = tanhf(glx[(4 + du) * 32 + b2]);
  float ov = sigf(glx[(6 + du) * 32 + b2]);
  float cn = fv * cs[du * 32 + b2] + iv * gv;
  cs[du * 32 + b2] = cn;
  bst(stP(o, hout_base + b2 * 512 + u), ov * tanhf(cn));
}

// ---------------------------------------------------------------------------
// Persistent kernel: all 64 timesteps, 2 grid barriers per step.
// Phase A (all 256 blocks): finish out(t-2) [ctx-half], L1(t), L0(t+1),
//   q(t-1), h1-half of out(t-1) -> oph (persistent LDS).
// Phase B (blocks 0..127, 4 per batch): softmax(q(t-1)) -> ctx(t-1).
// ---------------------------------------------------------------------------
#define SMEM_FLOATS 37200
#define SMEM_BYTES  (SMEM_FLOATS * 4)

__global__ void __launch_bounds__(256, 1) persist_kernel(
    float* o, const int* __restrict__ tokens, const float* __restrict__ emb,
    const float* __restrict__ Wih, const float* __restrict__ Whh,
    const float* __restrict__ bih, const float* __restrict__ bhh,
    const float* __restrict__ Wai, const float* __restrict__ Wao,
    const float* __restrict__ h0in, const float* __restrict__ c0in,
    const float* __restrict__ context,
    float* __restrict__ o_h, float* __restrict__ o_c, float* __restrict__ o_attn)
{
  extern __shared__ float smem[];
  float* wih0  = smem;            // 8*512
  float* whh0  = smem + 4096;
  float* wih1  = smem + 8192;
  float* whh1  = smem + 12288;
  float* waiL  = smem + 16384;    // 2*512
  float* waoL  = smem + 17408;    // 2*1024
  float* xs    = smem + 19456;    // 16384 staged input vectors
  float* gl    = smem + 35840;    // 256 (L1 gates / scores)
  float* gl2   = smem + 36096;    // 256 (L0 gates)
  float* gl3   = smem + 36352;    // 256 (q partials)
  float* glo   = smem + 36608;    // 256 (out ctx-half / ctx partials)
  float* oph   = smem + 36864;    // 128 (out h1-half partials, persistent)
  float* c0s   = smem + 36992;    // 64
  float* c1s   = smem + 37056;    // 64
  float* bias0 = smem + 37120;    // 8
  float* bias1 = smem + 37128;    // 8 (+pad)
  float* at_s  = smem + 37136;    // 64

  const int tid = threadIdx.x;
  const int bk  = blockIdx.x;
  const int b   = tid & 31;
  const int gq  = tid >> 5;
  unsigned g = 0;

  // ---- load persistent weights into LDS (once) ----
  for (int f = tid; f < 1024; f += 256) {        // 8 rows x 128 float4 each
    int r = f >> 7, k4 = f & 127;
    size_t j0 = (size_t)((r >> 1) * HID + bk * 2 + (r & 1));
    *(float4*)&wih0[r * 512 + k4 * 4] = *(const float4*)(Wih + j0 * HID + k4 * 4);
    *(float4*)&whh0[r * 512 + k4 * 4] = *(const float4*)(Whh + j0 * HID + k4 * 4);
    *(float4*)&wih1[r * 512 + k4 * 4] = *(const float4*)(Wih + 1048576 + j0 * HID + k4 * 4);
    *(float4*)&whh1[r * 512 + k4 * 4] = *(const float4*)(Whh + 1048576 + j0 * HID + k4 * 4);
  }
  {
    int r = tid >> 7, k4 = tid & 127;            // wai: 2 rows x 128 float4
    *(float4*)&waiL[r * 512 + k4 * 4] =
        *(const float4*)(Wai + (size_t)(bk * 2 + r) * HID + k4 * 4);
  }
  for (int f = tid; f < 512; f += 256) {         // wao: 2 rows x 256 float4
    int r = f >> 8, k4 = f & 255;
    *(float4*)&waoL[r * 1024 + k4 * 4] =
        *(const float4*)(Wao + (size_t)(bk * 2 + r) * 2 * HID + k4 * 4);
  }
  if (tid < 8) {
    int j0 = (tid >> 1) * HID + bk * 2 + (tid & 1);
    bias0[tid] = bih[j0] + bhh[j0];
    bias1[tid] = bih[2048 + j0] + bhh[2048 + j0];
  }
  // ---- P0: c state to LDS, h(-1) into buf1 bands ----
  if (tid < 64) {
    int b2 = tid & 31, du = tid >> 5, u = bk * 2 + du;
    c0s[du * 32 + b2] = c0in[b2 * 512 + u];
    c1s[du * 32 + b2] = c0in[16384 + b2 * 512 + u];
    bst(stP(o, 16384 + b2 * 512 + u), h0in[b2 * 512 + u]);          // h0(-1)
    bst(stP(o, 49152 + b2 * 512 + u), h0in[16384 + b2 * 512 + u]);  // h1(-1)
  }
  gsync(o, ++g);

  // ---- P1: L0(0) -> h0(0) (buf0) ----
  {
    stage_emb(tokens, emb, 0, xs); __syncthreads();
    float a0 = bias0[gq] + dotN<128>(xs, &wih0[gq * 512], 0, 0, b);
    __syncthreads();
    stage_band(o, 16384, xs); __syncthreads();                    // h0(-1)
    a0 += dotN<128>(xs, &whh0[gq * 512], 0, 0, b);
    gl2[tid] = a0; __syncthreads();
    if (tid >= 64 && tid < 128) gate_tail(o, gl2, c0s, bk, 0, tid - 64);
    gsync(o, ++g);
  }

  for (int t = 0; t < T_STEPS; ++t) {
    // ===== Phase A =====
    if (t >= 2) {                                                 // finish out(t-2)
      stage_band(o, 81920, xs); __syncthreads();                  // ctx(t-2)
      float cp = 0.f;
      if (gq < 4)
        cp = dotN<64>(xs, &waoL[(gq & 1) * 1024], (gq >> 1) * 64, (gq >> 1) * 256, b);
      glo[tid] = cp; __syncthreads();
      if (tid < 64) {
        int d = tid >> 5, b2 = tid & 31;
        float s = glo[d * 32 + b2] + glo[(2 + d) * 32 + b2]
                + oph[d * 32 + b2] + oph[(2 + d) * 32 + b2];
        o[(size_t)((t - 2) * BATCH + b2) * VOCAB + ABASE + bk * 2 + d] = tanhf(s);
      }
    }
    float a0 = 0.f;
    __syncthreads();
    if (t + 1 < T_STEPS) {
      stage_emb(tokens, emb, t + 1, xs); __syncthreads();
      a0 = bias0[gq] + dotN<128>(xs, &wih0[gq * 512], 0, 0, b);
    }
    __syncthreads();
    stage_band(o, (t & 1) * 16384, xs); __syncthreads();          // h0(t)
    if (t + 1 < T_STEPS) a0 += dotN<128>(xs, &whh0[gq * 512], 0, 0, b);
    float a1 = bias1[gq] + dotN<128>(xs, &wih1[gq * 512], 0, 0, b);
    __syncthreads();
    stage_band(o, 32768 + ((t + 1) & 1) * 16384, xs); __syncthreads();  // h1(t-1)
    a1 += dotN<128>(xs, &whh1[gq * 512], 0, 0, b);
    float qp = 0.f;
    if (t >= 1) {
      if (gq >= 4)                                                // h1-half of out(t-1)
        oph[(gq - 4) * 32 + b] =
            dotN<64>(xs, &waoL[(gq & 1) * 1024], ((gq >> 1) - 2) * 64,
                     512 + ((gq >> 1) - 2) * 256, b);
      qp = dotN<32>(xs, &waiL[(gq & 1) * 512], (gq >> 1) * 32, (gq >> 1) * 128, b);
    }
    gl[tid] = a1; gl2[tid] = a0; gl3[tid] = qp;
    __syncthreads();
    if (tid < 64) {
      gate_tail(o, gl, c1s, bk, 32768 + (t & 1) * 16384, tid);    // h1(t)
    } else if (tid < 128) {
      if (t + 1 < T_STEPS)
        gate_tail(o, gl2, c0s, bk, ((t + 1) & 1) * 16384, tid - 64); // h0(t+1)
    } else if (tid < 192 && t >= 1) {
      int tl = tid - 128, d = tl >> 5, b2 = tl & 31;
      float s = gl3[d * 32 + b2] + gl3[(2 + d) * 32 + b2]
              + gl3[(4 + d) * 32 + b2] + gl3[(6 + d) * 32 + b2];
      bst(stP(o, 65536 + b2 * 512 + bk * 2 + d), s);              // q(t-1)
    }
    gsync(o, ++g);

    // ===== Phase B: softmax/ctx(t-1), blocks 0..127 (4 per batch) =====
    if (bk < 128 && t >= 1) {
      const int bb = bk >> 2, qd = bk & 3;
      *(float2*)&xs[tid * 2] = bld2(stP(o, 65536 + bb * 512 + tid * 2));  // q
      __syncthreads();
      {
        int s = tid >> 2, kc = tid & 3;
        const float* crow = context + ((size_t)bb * SEQ + s) * HID + kc * 128;
        float ax = 0.f, ay = 0.f, az = 0.f, aw = 0.f;
#pragma unroll 8
        for (int i = 0; i < 32; ++i) {
          float4 c4 = *(const float4*)(crow + i * 4);
          const float* q4 = &xs[kc * 128 + i * 4];
          ax += c4.x * q4[0]; ay += c4.y * q4[1];
          az += c4.z * q4[2]; aw += c4.w * q4[3];
        }
        gl[tid] = (ax + ay) + (az + aw);
      }
      __syncthreads();
      if (tid < 64) {
        float sc = gl[tid * 4] + gl[tid * 4 + 1] + gl[tid * 4 + 2] + gl[tid * 4 + 3];
        float m = sc;
#pragma unroll
        for (int off = 32; off > 0; off >>= 1) m = fmaxf(m, __shfl_xor(m, off));
        float e = expf(sc - m);
        float su = e;
#pragma unroll
        for (int off = 32; off > 0; off >>= 1) su += __shfl_xor(su, off);
        at_s[tid] = e / su;
      }
      __syncthreads();
      {
        int h = qd * 128 + (tid & 127), sh = tid >> 7;
        const float* cb = context + (size_t)bb * SEQ * HID + h;
        float a2 = 0.f;
#pragma unroll 8
        for (int s2 = 0; s2 < 32; ++s2)
          a2 += at_s[sh * 32 + s2] * cb[(size_t)(sh * 32 + s2) * HID];
        glo[tid] = a2;
      }
      __syncthreads();
      if (tid < 128)
        bst(stP(o, 81920 + bb * 512 + qd * 128 + tid),
            glo[tid] + glo[tid + 128]);                           // ctx(t-1)
    }
    gsync(o, ++g);
  }

  // ===== E1: finish out(62); oph(63) + q(63) =====
  {
    stage_band(o, 81920, xs); __syncthreads();                    // ctx(62)
    float cp = 0.f;
    if (gq < 4)
      cp = dotN<64>(xs, &waoL[(gq & 1) * 1024], (gq >> 1) * 64, (gq >> 1) * 256, b);
    glo[tid] = cp; __syncthreads();
    if (tid < 64) {
      int d = tid >> 5, b2 = tid & 31;
      float s = glo[d * 32 + b2] + glo[(2 + d) * 32 + b2]
              + oph[d * 32 + b2] + oph[(2 + d) * 32 + b2];
      o[(size_t)(62 * BATCH + b2) * VOCAB + ABASE + bk * 2 + d] = tanhf(s);
    }
    __syncthreads();
    stage_band(o, 49152, xs); __syncthreads();                    // h1(63)
    if (gq >= 4)
      oph[(gq - 4) * 32 + b] =
          dotN<64>(xs, &waoL[(gq & 1) * 1024], ((gq >> 1) - 2) * 64,
                   512 + ((gq >> 1) - 2) * 256, b);
    float qp = dotN<32>(xs, &waiL[(gq & 1) * 512], (gq >> 1) * 32, (gq >> 1) * 128, b);
    gl3[tid] = qp; __syncthreads();
    if (tid >= 128 && tid < 192) {
      int tl = tid - 128, d = tl >> 5, b2 = tl & 31;
      float s = gl3[d * 32 + b2] + gl3[(2 + d) * 32 + b2]
              + gl3[(4 + d) * 32 + b2] + gl3[(6 + d) * 32 + b2];
      bst(stP(o, 65536 + b2 * 512 + bk * 2 + d), s);              // q(63)
    }
    gsync(o, ++g);
  }
  // ===== E2: softmax(63) -> ctx(63) + o_attn =====
  if (bk < 128) {
    const int bb = bk >> 2, qd = bk & 3;
    *(float2*)&xs[tid * 2] = bld2(stP(o, 65536 + bb * 512 + tid * 2));
    __syncthreads();
    {
      int s = tid >> 2, kc = tid & 3;
      const float* crow = context + ((size_t)bb * SEQ + s) * HID + kc * 128;
      float ax = 0.f, ay = 0.f, az = 0.f, aw = 0.f;
#pragma unroll 8
      for (int i = 0; i < 32; ++i) {
        float4 c4 = *(const float4*)(crow + i * 4);
        const float* q4 = &xs[kc * 128 + i * 4];
        ax += c4.x * q4[0]; ay += c4.y * q4[1];
        az += c4.z * q4[2]; aw += c4.w * q4[3];
      }
      gl[tid] = (ax + ay) + (az + aw);
    }
    __syncthreads();
    if (tid < 64) {
      float sc = gl[tid * 4] + gl[tid * 4 + 1] + gl[tid * 4 + 2] + gl[tid * 4 + 3];
      float m = sc;
#pragma unroll
      for (int off = 32; off > 0; off >>= 1) m = fmaxf(m, __shfl_xor(m, off));
      float e = expf(sc - m);
      float su = e;
#pragma unroll
      for (int off = 32; off > 0; off >>= 1) su += __shfl_xor(su, off);
      float av = e / su;
      at_s[tid] = av;
      if (qd == 0) o_attn[bb * SEQ + tid] = av;                   // attn(63)
    }
    __syncthreads();
    {
      int h = qd * 128 + (tid & 127), sh = tid >> 7;
      const float* cb = context + (size_t)bb * SEQ * HID + h;
      float a2 = 0.f;
#pragma unroll 8
      for (int s2 = 0; s2 < 32; ++s2)
        a2 += at_s[sh * 32 + s2] * cb[(size_t)(sh * 32 + s2) * HID];
      glo[tid] = a2;
    }
    __syncthreads();
    if (tid < 128)
      bst(stP(o, 81920 + bb * 512 + qd * 128 + tid),
          glo[tid] + glo[tid + 128]);                             // ctx(63)
  }
  gsync(o, ++g);
  // ===== E3: finish out(63); final states =====
  {
    stage_band(o, 81920, xs); __syncthreads();                    // ctx(63)
    float cp = 0.f;
    if (gq < 4)
      cp = dotN<64>(xs, &waoL[(gq & 1) * 1024], (gq >> 1) * 64, (gq >> 1) * 256, b);
    glo[tid] = cp; __syncthreads();
    if (tid < 64) {
      int d = tid >> 5, b2 = tid & 31;
      float s = glo[d * 32 + b2] + glo[(2 + d) * 32 + b2]
              + oph[d * 32 + b2] + oph[(2 + d) * 32 + b2];
      o[(size_t)(63 * BATCH + b2) * VOCAB + ABASE + bk * 2 + d] = tanhf(s);
    }
  }
  if (tid < 64) {
    int b2 = tid & 31, du = tid >> 5, u = bk * 2 + du;
    o_h[b2 * 512 + u]         = bld(stP(o, 16384 + b2 * 512 + u));    // h0(63) buf1
    o_h[16384 + b2 * 512 + u] = bld(stP(o, 49152 + b2 * 512 + u));    // h1(63) buf1
    o_c[b2 * 512 + u]         = c0s[du * 32 + b2];
    o_c[16384 + b2 * 512 + u] = c1s[du * 32 + b2];
  }
}

// ---------------------------------------------------------------------------
// vocab GEMM pass A: 490 col-tiles avoiding cols [16000,16640).
// ---------------------------------------------------------------------------
__device__ __forceinline__ short8 pack8(const float* p) {
  float4 a = *(const float4*)p, b = *(const float4*)(p + 4);
  short8 r;
  r[0] = (short)f2bf(a.x); r[1] = (short)f2bf(a.y);
  r[2] = (short)f2bf(a.z); r[3] = (short)f2bf(a.w);
  r[4] = (short)f2bf(b.x); r[5] = (short)f2bf(b.y);
  r[6] = (short)f2bf(b.z); r[7] = (short)f2bf(b.w);
  return r;
}

__global__ __launch_bounds__(256) void vocab_gemm_a(
    float* o, const float* __restrict__ Bw, const float* __restrict__ bias)
{
  __shared__ __align__(16) u16 As[4 * 64 * 8];
  __shared__ __align__(16) u16 Bs[4 * 64 * 8];
  const int tid = threadIdx.x;
  const int wv   = tid >> 6;
  const int lane = tid & 63;
  const int m16  = lane & 15;
  const int quad = lane >> 4;
  const int ct = (blockIdx.x < 250) ? blockIdx.x : blockIdx.x + 10;
  const int rowBase = blockIdx.y * 64;
  const int colBase = ct * 64;
  const int srow = tid >> 2;
  const int scg  = tid & 3;
  f32x4 acc[4];
#pragma unroll
  for (int nt = 0; nt < 4; ++nt)
#pragma unroll
    for (int r = 0; r < 4; ++r) acc[nt][r] = 0.f;

  for (int k0 = 0; k0 < HID; k0 += 32) {
    __syncthreads();
    *(short8*)&As[(scg * 64 + srow) * 8] =
        pack8(&o[(size_t)(rowBase + srow) * VOCAB + ABASE + k0 + scg * 8]);
    *(short8*)&Bs[(scg * 64 + srow) * 8] =
        pack8(&Bw[(size_t)(colBase + srow) * HID + k0 + scg * 8]);
    __syncthreads();
    short8 a = *(const short8*)&As[(quad * 64 + wv * 16 + m16) * 8];
#pragma unroll
    for (int nt = 0; nt < 4; ++nt) {
      short8 bfr = *(const short8*)&Bs[(quad * 64 + nt * 16 + m16) * 8];
      acc[nt] = __builtin_amdgcn_mfma_f32_16x16x32_bf16(a, bfr, acc[nt], 0, 0, 0);
    }
  }
#pragma unroll
  for (int nt = 0; nt < 4; ++nt) {
    int col = colBase + nt * 16 + m16;
    float bv = bias[col];
#pragma unroll
    for (int r = 0; r < 4; ++r) {
      int row = rowBase + wv * 16 + quad * 4 + r;
      o[(size_t)row * VOCAB + col] = acc[nt][r] + bv;
    }
  }
}

// ---------------------------------------------------------------------------
// pass B: the 10 band col-tiles. A staged to LDS BEFORE any write.
// ---------------------------------------------------------------------------
__global__ __launch_bounds__(256) void vocab_gemm_b(
    float* o, const float* __restrict__ Bw, const float* __restrict__ bias)
{
  __shared__ __align__(16) u16 As[32 * 512];   // 32 KB bf16
  const int tid = threadIdx.x;
  const int rowBase = blockIdx.x * 32;
  for (int i = tid; i < 2048; i += 256) {      // 2048 chunks of 8
    int r = i >> 6, kk = (i & 63) * 8;
    *(short8*)&As[r * 512 + kk] =
        pack8(&o[(size_t)(rowBase + r) * VOCAB + ABASE + kk]);
  }
  __syncthreads();
  const int lane = tid & 63, w = tid >> 6;
  const int m16 = lane & 15, quad = lane >> 4;
  const int rg = w & 1, cg = w >> 1;
  for (int ctile = 250; ctile < 260; ++ctile) {
    int colBase = ctile * 64 + cg * 32;
    f32x4 acc[2];
#pragma unroll
    for (int nt = 0; nt < 2; ++nt)
#pragma unroll
      for (int r = 0; r < 4; ++r) acc[nt][r] = 0.f;
    for (int k0 = 0; k0 < HID; k0 += 32) {
      short8 a = *(const short8*)&As[(rg * 16 + m16) * 512 + k0 + quad * 8];
#pragma unroll
      for (int nt = 0; nt < 2; ++nt) {
        short8 bfr = pack8(&Bw[(size_t)(colBase + nt * 16 + m16) * HID + k0 + quad * 8]);
        acc[nt] = __builtin_amdgcn_mfma_f32_16x16x32_bf16(a, bfr, acc[nt], 0, 0, 0);
      }
    }
#pragma unroll
    for (int nt = 0; nt < 2; ++nt) {
      int col = colBase + nt * 16 + m16;
      float bv = bias[col];
#pragma unroll
      for (int r = 0; r < 4; ++r) {
        int row = rowBase + rg * 16 + quad * 4 + r;
        o[(size_t)row * VOCAB + col] = acc[nt][r] + bv;
      }
    }
  }
}

// ---------------------------------------------------------------------------
// log-softmax over V=32000, 3-pass global (rows are L2/L3-hot)
// ---------------------------------------------------------------------------
__global__ __launch_bounds__(256) void logsoftmax_kernel(float* logits)
{
  __shared__ float red[256];
  const int tid = threadIdx.x;
  float* rowp = logits + (size_t)blockIdx.x * VOCAB;
  float mx = -1e30f;
  for (int i = tid; i < VOCAB / 4; i += 256) {
    float4 v = ((const float4*)rowp)[i];
    mx = fmaxf(mx, fmaxf(fmaxf(v.x, v.y), fmaxf(v.z, v.w)));
  }
  red[tid] = mx; __syncthreads();
  for (int s = 128; s > 0; s >>= 1) {
    if (tid < s) red[tid] = fmaxf(red[tid], red[tid + s]);
    __syncthreads();
  }
  mx = red[0]; __syncthreads();
  float sum = 0.f;
  for (int i = tid; i < VOCAB / 4; i += 256) {
    float4 v = ((const float4*)rowp)[i];
    sum += expf(v.x - mx) + expf(v.y - mx) + expf(v.z - mx) + expf(v.w - mx);
  }
  red[tid] = sum; __syncthreads();
  for (int s = 128; s > 0; s >>= 1) {
    if (tid < s) red[tid] += red[tid + s];
    __syncthreads();
  }
  float lse = mx + logf(red[0]);
  for (int i = tid; i < VOCAB / 4; i += 256) {
    float4 v = ((const float4*)rowp)[i];
    float4 ov;
    ov.x = v.x - lse; ov.y = v.y - lse; ov.z = v.z - lse; ov.w = v.w - lse;
    ((float4*)rowp)[i] = ov;
  }
}

// ---------------------------------------------------------------------------
extern "C" void kernel_launch(void* const* d_in, const int* in_sizes, int n_in,
                              void* d_out, int out_size, void* d_ws, size_t ws_size,
                              hipStream_t stream)
{
  (void)in_sizes; (void)n_in; (void)out_size; (void)d_ws; (void)ws_size;
  const int*   tokens  = (const int*)d_in[0];
  const float* h0      = (const float*)d_in[1];
  const float* c0      = (const float*)d_in[2];
  const float* context = (const float*)d_in[3];
  const float* emb     = (const float*)d_in[4];
  const float* Wih     = (const float*)d_in[5];
  const float* Whh     = (const float*)d_in[6];
  const float* bih     = (const float*)d_in[7];
  const float* bhh     = (const float*)d_in[8];
  const float* Wai     = (const float*)d_in[9];
  const float* Wao     = (const float*)d_in[10];
  const float* Wlin    = (const float*)d_in[11];
  const float* blin    = (const float*)d_in[12];

  float* o      = (float*)d_out;
  float* o_h    = o + (size_t)2048 * VOCAB;
  float* o_c    = o_h + 32768;
  float* o_attn = o_c + 32768;

  // zero the sync words (band rows 1536..1541, 256B each; graph-capture safe)
  for (int r = 0; r < 6; ++r)
    hipMemsetAsync(o + (size_t)(1536 + r) * VOCAB + SBASE, 0, 256, stream);

  hipFuncSetAttribute((const void*)persist_kernel,
                      hipFuncAttributeMaxDynamicSharedMemorySize, SMEM_BYTES);
  persist_kernel<<<NBLK, 256, SMEM_BYTES, stream>>>(
      o, tokens, emb, Wih, Whh, bih, bhh, Wai, Wao,
      h0, c0, context, o_h, o_c, o_attn);

  vocab_gemm_a<<<dim3(490, 32), 256, 0, stream>>>(o, Wlin, blin);
  vocab_gemm_b<<<64, 256, 0, stream>>>(o, Wlin, blin);
  logsoftmax_kernel<<<2048, 256, 0, stream>>>(o);
}

// Round 5
// 3869.233 us; speedup vs baseline: 3.2185x; 1.3018x over previous
//
#include <hip/hip_runtime.h>
#include <math.h>

#define T_STEPS 64
#define BATCH   32
#define SEQ     64
#define HID     512
#define VOCAB   32000
#define ABASE   16000   // outs (A-matrix) band: f32 cols [16000,16512) of each logits row
#define SBASE   16512   // fp32 state band: f32 cols [16512,16576)
#define NBLK    256

typedef unsigned short u16;
typedef unsigned int   u32;

typedef __attribute__((ext_vector_type(8))) short short8;
typedef __attribute__((ext_vector_type(4))) float f32x4;

#define AS_RLX __ATOMIC_RELAXED
#define SC_AGT __HIP_MEMORY_SCOPE_AGENT

__device__ __forceinline__ u16 f2bf(float f) {
  u32 x = __float_as_uint(f);
  u32 r = (x + 0x7fffu + ((x >> 16) & 1u)) >> 16;
  return (u16)r;
}
__device__ __forceinline__ float sigf(float x) { return 1.0f / (1.0f + expf(-x)); }

// fp32 state element i lives at logits row (i>>6), f32 col SBASE + (i&63).
__device__ __forceinline__ float* stP(float* o, int i) {
  return o + (size_t)(i >> 6) * VOCAB + SBASE + (i & 63);
}
// state map (floats): h0 bufs @ 0/16384 (h0(t) in buf[t&1]);
//                     h1 bufs @ 32768/49152 (h1(t) in buf[t&1]);
//                     q bufs @ 65536/81920 (q(s) in buf[s&1]);
//                     ctx bufs @ 98304/114688 (ctx(s) in buf[s&1]).

// ---- coherent (agent-scope, L2-bypassing) band accessors -------------------
__device__ __forceinline__ void bst(float* p, float v) {
  __hip_atomic_store(p, v, AS_RLX, SC_AGT);
}
__device__ __forceinline__ float bld(const float* p) {
  return __hip_atomic_load(p, AS_RLX, SC_AGT);
}
__device__ __forceinline__ float4 bld4(const float* p) {
  float4 r;
  r.x = __hip_atomic_load(p + 0, AS_RLX, SC_AGT);
  r.y = __hip_atomic_load(p + 1, AS_RLX, SC_AGT);
  r.z = __hip_atomic_load(p + 2, AS_RLX, SC_AGT);
  r.w = __hip_atomic_load(p + 3, AS_RLX, SC_AGT);
  return r;
}

// sync word i -> logits rows 0..5, cols 17024.. (overwritten later by gemm_a)
__device__ __forceinline__ unsigned* syncW(float* o, int i) {
  return (unsigned*)(o + (size_t)(i >> 6) * VOCAB + 17024 + (i & 63));
}

// spin until *w >= g; self-healing periodic fence prevents any livelock.
__device__ __forceinline__ void spin_until(unsigned* w, unsigned g) {
  int k = 0;
  while (__hip_atomic_load(w, AS_RLX, SC_AGT) < g) {
    __builtin_amdgcn_s_sleep(2);
    if (++k == 16384) { k = 0; __threadfence(); }
  }
}

// fence-free grid barrier (state is sc1 write-through; release = vmcnt drain).
__device__ __forceinline__ void gsync(float* o, unsigned g) {
  asm volatile("s_waitcnt vmcnt(0)" ::: "memory");
  __syncthreads();
  const int tid = threadIdx.x;
  if (blockIdx.x == 0) {
    if (tid >= 1) spin_until(syncW(o, tid), g);
    __syncthreads();
    if (tid == 0)
      __hip_atomic_store(syncW(o, 320), g, AS_RLX, SC_AGT);
  } else {
    if (tid == 0) {
      __hip_atomic_store(syncW(o, blockIdx.x), g, AS_RLX, SC_AGT);
      spin_until(syncW(o, 320), g);
    }
  }
  __syncthreads();
}

// ---------------------------------------------------------------------------
// xs staging: 32 batches x 512 floats as float4 slots [k4][b], XOR-swizzled.
// ---------------------------------------------------------------------------
__device__ __forceinline__ int xslot(int k4, int bb) {
  return (k4 * 32 + (bb ^ (k4 & 7))) * 4;
}
__device__ __forceinline__ void stage_band(float* o, int base, float* xs) {
  const int tid = threadIdx.x;
#pragma unroll
  for (int it = 0; it < 16; ++it) {
    int f = it * 256 + tid;
    int bb = f >> 7, k4 = f & 127;
    *(float4*)&xs[xslot(k4, bb)] = bld4(stP(o, base + bb * 512 + k4 * 4));
  }
}
__device__ __forceinline__ void stage_emb(const int* __restrict__ tokens,
                                          const float* __restrict__ emb,
                                          int t, float* xs) {
  const int tid = threadIdx.x;
#pragma unroll
  for (int it = 0; it < 16; ++it) {
    int f = it * 256 + tid;
    int bb = f >> 7, k4 = f & 127;
    int tok = tokens[bb * T_STEPS + t];
    *(float4*)&xs[xslot(k4, bb)] = *(const float4*)(emb + (size_t)tok * HID + k4 * 4);
  }
}
template <int N>
__device__ __forceinline__ float dotN(const float* xs, const float* wrow,
                                      int k4base, int wofs, int bb) {
  float ax = 0.f, ay = 0.f, az = 0.f, aw = 0.f;
#pragma unroll 8
  for (int i = 0; i < N; ++i) {
    int k4 = k4base + i;
    float4 x = *(const float4*)&xs[xslot(k4, bb)];
    float4 w = *(const float4*)&wrow[wofs + i * 4];
    ax += w.x * x.x; ay += w.y * x.y; az += w.z * x.z; aw += w.w * x.w;
  }
  return (ax + ay) + (az + aw);
}
// glx[gq*32+b], gq = q*2+du (q = gate 0..3, du = unit 0..1); cs LDS c-state.
__device__ __forceinline__ void gate_tail(float* o, const float* glx, float* cs,
                                          int bk, int hout_base, int tl) {
  int b2 = tl & 31, du = tl >> 5, u = bk * 2 + du;
  float iv = sigf(glx[du * 32 + b2]);
  float fv = sigf(glx[(2 + du) * 32 + b2]);
  float gv = tanhf(glx[(4 + du) * 32 + b2]);
  float ov = sigf(glx[(6 + du) * 32 + b2]);
  float cn = fv * cs[du * 32 + b2] + iv * gv;
  cs[du * 32 + b2] = cn;
  bst(stP(o, hout_base + b2 * 512 + u), ov * tanhf(cn));
}

// ---------------------------------------------------------------------------
// Persistent kernel: all 64 timesteps, ONE grid barrier per step.
// A'(t): finish out(t-3) | L1(t) | L0(t+1) | q(t-1), oph(t-1) |
//        attention(t-2): softmax q(t-2) -> ctx(t-2) (8 blocks/batch, 64-slice)
// ---------------------------------------------------------------------------
#define SMEM_FLOATS 37336
#define SMEM_BYTES  (SMEM_FLOATS * 4)

__global__ void __launch_bounds__(256, 1) persist_kernel(
    float* o, const int* __restrict__ tokens, const float* __restrict__ emb,
    const float* __restrict__ Wih, const float* __restrict__ Whh,
    const float* __restrict__ bih, const float* __restrict__ bhh,
    const float* __restrict__ Wai, const float* __restrict__ Wao,
    const float* __restrict__ h0in, const float* __restrict__ c0in,
    const float* __restrict__ context,
    float* __restrict__ o_h, float* __restrict__ o_c, float* __restrict__ o_attn)
{
  extern __shared__ float smem[];
  float* wih0  = smem;            // 8*512
  float* whh0  = smem + 4096;
  float* wih1  = smem + 8192;
  float* whh1  = smem + 12288;
  float* waiL  = smem + 16384;    // 2*512
  float* waoL  = smem + 17408;    // 2*1024
  float* xs    = smem + 19456;    // 16384 staged input vectors
  float* gl    = smem + 35840;    // 256 (L1 gates / scores)
  float* gl2   = smem + 36096;    // 256 (L0 gates)
  float* gl3   = smem + 36352;    // 256 (q partials)
  float* glo   = smem + 36608;    // 256 (out ctx-half / ctx partials)
  float* oph   = smem + 36864;    // 2*128 (out h1-half partials, alternating)
  float* c0s   = smem + 37120;    // 64
  float* c1s   = smem + 37184;    // 64
  float* bias0 = smem + 37248;    // 8
  float* bias1 = smem + 37256;    // 8
  float* at_s  = smem + 37264;    // 64 (+pad)

  const int tid = threadIdx.x;
  const int bk  = blockIdx.x;
  const int b   = tid & 31;
  const int gq  = tid >> 5;
  unsigned g = 0;

  // ---- load persistent weights into LDS (once) ----
  for (int f = tid; f < 1024; f += 256) {        // 8 rows x 128 float4 each
    int r = f >> 7, k4 = f & 127;
    size_t j0 = (size_t)((r >> 1) * HID + bk * 2 + (r & 1));
    *(float4*)&wih0[r * 512 + k4 * 4] = *(const float4*)(Wih + j0 * HID + k4 * 4);
    *(float4*)&whh0[r * 512 + k4 * 4] = *(const float4*)(Whh + j0 * HID + k4 * 4);
    *(float4*)&wih1[r * 512 + k4 * 4] = *(const float4*)(Wih + 1048576 + j0 * HID + k4 * 4);
    *(float4*)&whh1[r * 512 + k4 * 4] = *(const float4*)(Whh + 1048576 + j0 * HID + k4 * 4);
  }
  {
    int r = tid >> 7, k4 = tid & 127;            // wai: 2 rows x 128 float4
    *(float4*)&waiL[r * 512 + k4 * 4] =
        *(const float4*)(Wai + (size_t)(bk * 2 + r) * HID + k4 * 4);
  }
  for (int f = tid; f < 512; f += 256) {         // wao: 2 rows x 256 float4
    int r = f >> 8, k4 = f & 255;
    *(float4*)&waoL[r * 1024 + k4 * 4] =
        *(const float4*)(Wao + (size_t)(bk * 2 + r) * 2 * HID + k4 * 4);
  }
  if (tid < 8) {
    int j0 = (tid >> 1) * HID + bk * 2 + (tid & 1);
    bias0[tid] = bih[j0] + bhh[j0];
    bias1[tid] = bih[2048 + j0] + bhh[2048 + j0];
  }
  // ---- P0: c state to LDS, h(-1) into buf1 bands ----
  if (tid < 64) {
    int b2 = tid & 31, du = tid >> 5, u = bk * 2 + du;
    c0s[du * 32 + b2] = c0in[b2 * 512 + u];
    c1s[du * 32 + b2] = c0in[16384 + b2 * 512 + u];
    bst(stP(o, 16384 + b2 * 512 + u), h0in[b2 * 512 + u]);          // h0(-1)
    bst(stP(o, 49152 + b2 * 512 + u), h0in[16384 + b2 * 512 + u]);  // h1(-1)
  }
  gsync(o, ++g);

  // ---- P1: L0(0) -> h0(0) (buf0) ----
  {
    stage_emb(tokens, emb, 0, xs); __syncthreads();
    float a0 = bias0[gq] + dotN<128>(xs, &wih0[gq * 512], 0, 0, b);
    __syncthreads();
    stage_band(o, 16384, xs); __syncthreads();                    // h0(-1)
    a0 += dotN<128>(xs, &whh0[gq * 512], 0, 0, b);
    gl2[tid] = a0; __syncthreads();
    if (tid >= 64 && tid < 128) gate_tail(o, gl2, c0s, bk, 0, tid - 64);
    gsync(o, ++g);
  }

  for (int t = 0; t <= T_STEPS + 2; ++t) {       // t = 0..66
    // ===== finish out(t-3): ctx-half + oph =====
    if (t >= 3) {
      stage_band(o, 98304 + ((t + 1) & 1) * 16384, xs); __syncthreads(); // ctx(t-3)
      float cp = 0.f;
      if (gq < 4)
        cp = dotN<64>(xs, &waoL[(gq & 1) * 1024], (gq >> 1) * 64, (gq >> 1) * 256, b);
      glo[tid] = cp; __syncthreads();
      if (tid < 64) {
        int d = tid >> 5, b2 = tid & 31;
        float* op = &oph[((t - 3) & 1) * 128];
        float s = glo[d * 32 + b2] + glo[(2 + d) * 32 + b2]
                + op[d * 32 + b2] + op[(2 + d) * 32 + b2];
        o[(size_t)((t - 3) * BATCH + b2) * VOCAB + ABASE + bk * 2 + d] = tanhf(s);
      }
      __syncthreads();
    }
    // ===== L0(t+1) part 1: emb =====
    float a0 = 0.f, a1 = 0.f, qp = 0.f;
    if (t + 1 < T_STEPS) {
      stage_emb(tokens, emb, t + 1, xs); __syncthreads();
      a0 = bias0[gq] + dotN<128>(xs, &wih0[gq * 512], 0, 0, b);
      __syncthreads();
    }
    // ===== h0(t) pass: whh0 + wih1 =====
    if (t < T_STEPS) {
      stage_band(o, (t & 1) * 16384, xs); __syncthreads();
      if (t + 1 < T_STEPS) a0 += dotN<128>(xs, &whh0[gq * 512], 0, 0, b);
      a1 = bias1[gq] + dotN<128>(xs, &wih1[gq * 512], 0, 0, b);
      __syncthreads();
    }
    // ===== h1(t-1) pass: whh1 + oph(t-1) + q(t-1) =====
    if (t <= T_STEPS) {
      stage_band(o, 32768 + ((t + 1) & 1) * 16384, xs); __syncthreads();
      if (t < T_STEPS) a1 += dotN<128>(xs, &whh1[gq * 512], 0, 0, b);
      if (t >= 1) {
        if (gq >= 4)
          oph[((t - 1) & 1) * 128 + (gq - 4) * 32 + b] =
              dotN<64>(xs, &waoL[(gq & 1) * 1024], ((gq >> 1) - 2) * 64,
                       512 + ((gq >> 1) - 2) * 256, b);
        qp = dotN<32>(xs, &waiL[(gq & 1) * 512], (gq >> 1) * 32, (gq >> 1) * 128, b);
      }
    }
    // ===== tails =====
    gl[tid] = a1; gl2[tid] = a0; gl3[tid] = qp;
    __syncthreads();
    if (tid < 64) {
      if (t < T_STEPS)
        gate_tail(o, gl, c1s, bk, 32768 + (t & 1) * 16384, tid);      // h1(t)
    } else if (tid < 128) {
      if (t + 1 < T_STEPS)
        gate_tail(o, gl2, c0s, bk, ((t + 1) & 1) * 16384, tid - 64);  // h0(t+1)
    } else if (tid < 192) {
      if (t >= 1 && t <= T_STEPS) {
        int tl = tid - 128, d = tl >> 5, b2 = tl & 31;
        float s = gl3[d * 32 + b2] + gl3[(2 + d) * 32 + b2]
                + gl3[(4 + d) * 32 + b2] + gl3[(6 + d) * 32 + b2];
        bst(stP(o, 65536 + ((t - 1) & 1) * 16384 + b2 * 512 + bk * 2 + d), s); // q(t-1)
      }
    }
    __syncthreads();
    // ===== attention(t-2): 8 blocks per batch, 64-component ctx slice =====
    if (t >= 2 && t <= T_STEPS + 1) {
      const int bb = bk >> 3, sl = bk & 7;
      if (tid < 128)
        *(float4*)&xs[tid * 4] =
            bld4(stP(o, 65536 + (t & 1) * 16384 + bb * 512 + tid * 4));  // q(t-2)
      __syncthreads();
      {
        int s = tid >> 2, kc = tid & 3;
        const float* crow = context + ((size_t)bb * SEQ + s) * HID + kc * 128;
        float ax = 0.f, ay = 0.f, az = 0.f, aw = 0.f;
#pragma unroll 8
        for (int i = 0; i < 32; ++i) {
          float4 c4 = *(const float4*)(crow + i * 4);
          const float* q4 = &xs[kc * 128 + i * 4];
          ax += c4.x * q4[0]; ay += c4.y * q4[1];
          az += c4.z * q4[2]; aw += c4.w * q4[3];
        }
        gl[tid] = (ax + ay) + (az + aw);
      }
      __syncthreads();
      if (tid < 64) {
        float sc = gl[tid * 4] + gl[tid * 4 + 1] + gl[tid * 4 + 2] + gl[tid * 4 + 3];
        float m = sc;
#pragma unroll
        for (int off = 32; off > 0; off >>= 1) m = fmaxf(m, __shfl_xor(m, off));
        float e = expf(sc - m);
        float su = e;
#pragma unroll
        for (int off = 32; off > 0; off >>= 1) su += __shfl_xor(su, off);
        float av = e / su;
        at_s[tid] = av;
        if (t == T_STEPS + 1 && sl == 0) o_attn[bb * SEQ + tid] = av;  // attn(63)
      }
      __syncthreads();
      {
        int h = sl * 64 + (tid & 63), sh = tid >> 6;
        const float* cb = context + (size_t)bb * SEQ * HID + h;
        float a2 = 0.f;
#pragma unroll 8
        for (int s2 = sh * 16; s2 < sh * 16 + 16; ++s2)
          a2 += at_s[s2] * cb[(size_t)s2 * HID];
        glo[tid] = a2;
      }
      __syncthreads();
      if (tid < 64)
        bst(stP(o, 98304 + (t & 1) * 16384 + bb * 512 + sl * 64 + tid),
            glo[tid] + glo[tid + 64] + glo[tid + 128] + glo[tid + 192]); // ctx(t-2)
    }
    gsync(o, ++g);
  }

  // ===== final states =====
  if (tid < 64) {
    int b2 = tid & 31, du = tid >> 5, u = bk * 2 + du;
    o_h[b2 * 512 + u]         = bld(stP(o, 16384 + b2 * 512 + u));    // h0(63) buf1
    o_h[16384 + b2 * 512 + u] = bld(stP(o, 49152 + b2 * 512 + u));    // h1(63) buf1
    o_c[b2 * 512 + u]         = c0s[du * 32 + b2];
    o_c[16384 + b2 * 512 + u] = c1s[du * 32 + b2];
  }
}

// ---------------------------------------------------------------------------
// vocab GEMM pass A: 490 col-tiles avoiding cols [16000,16640).
// ---------------------------------------------------------------------------
__device__ __forceinline__ short8 pack8(const float* p) {
  float4 a = *(const float4*)p, b = *(const float4*)(p + 4);
  short8 r;
  r[0] = (short)f2bf(a.x); r[1] = (short)f2bf(a.y);
  r[2] = (short)f2bf(a.z); r[3] = (short)f2bf(a.w);
  r[4] = (short)f2bf(b.x); r[5] = (short)f2bf(b.y);
  r[6] = (short)f2bf(b.z); r[7] = (short)f2bf(b.w);
  return r;
}

__global__ __launch_bounds__(256) void vocab_gemm_a(
    float* o, const float* __restrict__ Bw, const float* __restrict__ bias)
{
  __shared__ __align__(16) u16 As[4 * 64 * 8];
  __shared__ __align__(16) u16 Bs[4 * 64 * 8];
  const int tid = threadIdx.x;
  const int wv   = tid >> 6;
  const int lane = tid & 63;
  const int m16  = lane & 15;
  const int quad = lane >> 4;
  const int ct = (blockIdx.x < 250) ? blockIdx.x : blockIdx.x + 10;
  const int rowBase = blockIdx.y * 64;
  const int colBase = ct * 64;
  const int srow = tid >> 2;
  const int scg  = tid & 3;
  f32x4 acc[4];
#pragma unroll
  for (int nt = 0; nt < 4; ++nt)
#pragma unroll
    for (int r = 0; r < 4; ++r) acc[nt][r] = 0.f;

  for (int k0 = 0; k0 < HID; k0 += 32) {
    __syncthreads();
    *(short8*)&As[(scg * 64 + srow) * 8] =
        pack8(&o[(size_t)(rowBase + srow) * VOCAB + ABASE + k0 + scg * 8]);
    *(short8*)&Bs[(scg * 64 + srow) * 8] =
        pack8(&Bw[(size_t)(colBase + srow) * HID + k0 + scg * 8]);
    __syncthreads();
    short8 a = *(const short8*)&As[(quad * 64 + wv * 16 + m16) * 8];
#pragma unroll
    for (int nt = 0; nt < 4; ++nt) {
      short8 bfr = *(const short8*)&Bs[(quad * 64 + nt * 16 + m16) * 8];
      acc[nt] = __builtin_amdgcn_mfma_f32_16x16x32_bf16(a, bfr, acc[nt], 0, 0, 0);
    }
  }
#pragma unroll
  for (int nt = 0; nt < 4; ++nt) {
    int col = colBase + nt * 16 + m16;
    float bv = bias[col];
#pragma unroll
    for (int r = 0; r < 4; ++r) {
      int row = rowBase + wv * 16 + quad * 4 + r;
      o[(size_t)row * VOCAB + col] = acc[nt][r] + bv;
    }
  }
}

// ---------------------------------------------------------------------------
// pass B: the 10 band col-tiles. A staged to LDS BEFORE any write.
// ---------------------------------------------------------------------------
__global__ __launch_bounds__(256) void vocab_gemm_b(
    float* o, const float* __restrict__ Bw, const float* __restrict__ bias)
{
  __shared__ __align__(16) u16 As[32 * 512];   // 32 KB bf16
  const int tid = threadIdx.x;
  const int rowBase = blockIdx.x * 32;
  for (int i = tid; i < 2048; i += 256) {      // 2048 chunks of 8
    int r = i >> 6, kk = (i & 63) * 8;
    *(short8*)&As[r * 512 + kk] =
        pack8(&o[(size_t)(rowBase + r) * VOCAB + ABASE + kk]);
  }
  __syncthreads();
  const int lane = tid & 63, w = tid >> 6;
  const int m16 = lane & 15, quad = lane >> 4;
  const int rg = w & 1, cg = w >> 1;
  for (int ctile = 250; ctile < 260; ++ctile) {
    int colBase = ctile * 64 + cg * 32;
    f32x4 acc[2];
#pragma unroll
    for (int nt = 0; nt < 2; ++nt)
#pragma unroll
      for (int r = 0; r < 4; ++r) acc[nt][r] = 0.f;
    for (int k0 = 0; k0 < HID; k0 += 32) {
      short8 a = *(const short8*)&As[(rg * 16 + m16) * 512 + k0 + quad * 8];
#pragma unroll
      for (int nt = 0; nt < 2; ++nt) {
        short8 bfr = pack8(&Bw[(size_t)(colBase + nt * 16 + m16) * HID + k0 + quad * 8]);
        acc[nt] = __builtin_amdgcn_mfma_f32_16x16x32_bf16(a, bfr, acc[nt], 0, 0, 0);
      }
    }
#pragma unroll
    for (int nt = 0; nt < 2; ++nt) {
      int col = colBase + nt * 16 + m16;
      float bv = bias[col];
#pragma unroll
      for (int r = 0; r < 4; ++r) {
        int row = rowBase + rg * 16 + quad * 4 + r;
        o[(size_t)row * VOCAB + col] = acc[nt][r] + bv;
      }
    }
  }
}

// ---------------------------------------------------------------------------
// log-softmax over V=32000, 3-pass global (rows are L2/L3-hot)
// ---------------------------------------------------------------------------
__global__ __launch_bounds__(256) void logsoftmax_kernel(float* logits)
{
  __shared__ float red[256];
  const int tid = threadIdx.x;
  float* rowp = logits + (size_t)blockIdx.x * VOCAB;
  float mx = -1e30f;
  for (int i = tid; i < VOCAB / 4; i += 256) {
    float4 v = ((const float4*)rowp)[i];
    mx = fmaxf(mx, fmaxf(fmaxf(v.x, v.y), fmaxf(v.z, v.w)));
  }
  red[tid] = mx; __syncthreads();
  for (int s = 128; s > 0; s >>= 1) {
    if (tid < s) red[tid] = fmaxf(red[tid], red[tid + s]);
    __syncthreads();
  }
  mx = red[0]; __syncthreads();
  float sum = 0.f;
  for (int i = tid; i < VOCAB / 4; i += 256) {
    float4 v = ((const float4*)rowp)[i];
    sum += expf(v.x - mx) + expf(v.y - mx) + expf(v.z - mx) + expf(v.w - mx);
  }
  red[tid] = sum; __syncthreads();
  for (int s = 128; s > 0; s >>= 1) {
    if (tid < s) red[tid] += red[tid + s];
    __syncthreads();
  }
  float lse = mx + logf(red[0]);
  for (int i = tid; i < VOCAB / 4; i += 256) {
    float4 v = ((const float4*)rowp)[i];
    float4 ov;
    ov.x = v.x - lse; ov.y = v.y - lse; ov.z = v.z - lse; ov.w = v.w - lse;
    ((float4*)rowp)[i] = ov;
  }
}

// ---------------------------------------------------------------------------
extern "C" void kernel_launch(void* const* d_in, const int* in_sizes, int n_in,
                              void* d_out, int out_size, void* d_ws, size_t ws_size,
                              hipStream_t stream)
{
  (void)in_sizes; (void)n_in; (void)out_size; (void)d_ws; (void)ws_size;
  const int*   tokens  = (const int*)d_in[0];
  const float* h0      = (const float*)d_in[1];
  const float* c0      = (const float*)d_in[2];
  const float* context = (const float*)d_in[3];
  const float* emb     = (const float*)d_in[4];
  const float* Wih     = (const float*)d_in[5];
  const float* Whh     = (const float*)d_in[6];
  const float* bih     = (const float*)d_in[7];
  const float* bhh     = (const float*)d_in[8];
  const float* Wai     = (const float*)d_in[9];
  const float* Wao     = (const float*)d_in[10];
  const float* Wlin    = (const float*)d_in[11];
  const float* blin    = (const float*)d_in[12];

  float* o      = (float*)d_out;
  float* o_h    = o + (size_t)2048 * VOCAB;
  float* o_c    = o_h + 32768;
  float* o_attn = o_c + 32768;

  // zero the sync words (rows 0..5, col 17024; overwritten later by gemm_a)
  for (int r = 0; r < 6; ++r)
    hipMemsetAsync(o + (size_t)r * VOCAB + 17024, 0, 256, stream);

  hipFuncSetAttribute((const void*)persist_kernel,
                      hipFuncAttributeMaxDynamicSharedMemorySize, SMEM_BYTES);
  persist_kernel<<<NBLK, 256, SMEM_BYTES, stream>>>(
      o, tokens, emb, Wih, Whh, bih, bhh, Wai, Wao,
      h0, c0, context, o_h, o_c, o_attn);

  vocab_gemm_a<<<dim3(490, 32), 256, 0, stream>>>(o, Wlin, blin);
  vocab_gemm_b<<<64, 256, 0, stream>>>(o, Wlin, blin);
  logsoftmax_kernel<<<2048, 256, 0, stream>>>(o);
}